// Round 8
// baseline (1657.774 us; speedup 1.0000x reference)
//
#include <hip/hip_runtime.h>

#define DF   128    // feature dim
#define EPB  1024   // elements per scan block
#define MAXB 512    // max level-2 scan width (supports M <= 524288)
#define TPB  64     // nodes per block-tile
#define AST  132    // Atf row stride in floats (128 + 4)
#define WSTS 136    // Wt row stride in shorts  (128 + 8)

typedef __attribute__((ext_vector_type(8))) short short8;
typedef __attribute__((ext_vector_type(4))) float f32x4;

__device__ __forceinline__ unsigned short f2bf(float x) {
    unsigned u = __float_as_uint(x);
    u = (u + 0x7FFFu + ((u >> 16) & 1u)) >> 16;   // RNE
    return (unsigned short)u;
}
__device__ __forceinline__ unsigned pack2bf(float a, float b) {
    return (unsigned)f2bf(a) | ((unsigned)f2bf(b) << 16);
}
__device__ __forceinline__ int rfl(int x) {
    return __builtin_amdgcn_readfirstlane(x);
}

// ===========================================================================
// CSR build: count degrees -> exclusive scan -> place edge ids.
// Node space M = [66: 0..N6) [86: N6..2N6) [68: 2N6..2N6+N8) [88: ...+N8)
// Edge space  = [66: 0..E66) [86 ...) [68 ...) [88 ...)  (global gid)
// ===========================================================================

__global__ void __launch_bounds__(256) count_kernel(
    const int* __restrict__ ei66, const int* __restrict__ ei86,
    const int* __restrict__ ei68, const int* __restrict__ ei88,
    int E66, int E86, int E68, int E88, int N6, int N8,
    int* __restrict__ base)
{
    int Etot = E66 + E86 + E68 + E88;
    for (int gid = blockIdx.x * 256 + threadIdx.x; gid < Etot;
         gid += gridDim.x * 256) {
        int le = gid, nb, dst;
        if (le < E66)               { dst = ei66[2 * le + 1]; nb = 0; }
        else if ((le -= E66) < E86) { dst = ei86[2 * le + 1]; nb = N6; }
        else if ((le -= E86) < E68) { dst = ei68[2 * le + 1]; nb = 2 * N6; }
        else { le -= E68;             dst = ei88[2 * le + 1]; nb = 2 * N6 + N8; }
        atomicAdd(base + nb + dst, 1);
    }
}

__global__ void __launch_bounds__(256) scan1_kernel(
    int* __restrict__ data, int M, int* __restrict__ bsum)
{
    __shared__ int ts[256];
    int t = threadIdx.x;
    int i0 = blockIdx.x * EPB + t * 4;
    int v0 = 0, v1 = 0, v2 = 0, v3 = 0;
    if (i0 + 3 < M) {
        int4 q = *(const int4*)(data + i0);
        v0 = q.x; v1 = q.y; v2 = q.z; v3 = q.w;
    } else {
        if (i0     < M) v0 = data[i0];
        if (i0 + 1 < M) v1 = data[i0 + 1];
        if (i0 + 2 < M) v2 = data[i0 + 2];
    }
    int sum = v0 + v1 + v2 + v3;
    ts[t] = sum;
    __syncthreads();
    for (int off = 1; off < 256; off <<= 1) {
        int x = (t >= off) ? ts[t - off] : 0;
        __syncthreads();
        ts[t] += x;
        __syncthreads();
    }
    int excl = ts[t] - sum;
    if (t == 255) bsum[blockIdx.x] = ts[255];
    int w0 = excl, w1 = excl + v0, w2 = w1 + v1, w3 = w2 + v2;
    if (i0 + 3 < M) {
        *(int4*)(data + i0) = make_int4(w0, w1, w2, w3);
    } else {
        if (i0     < M) data[i0]     = w0;
        if (i0 + 1 < M) data[i0 + 1] = w1;
        if (i0 + 2 < M) data[i0 + 2] = w2;
    }
}

__global__ void __launch_bounds__(256) scan2_kernel(int* __restrict__ bsum, int nb)
{
    __shared__ int s[MAXB];
    int t = threadIdx.x;
    s[t]       = (t       < nb) ? bsum[t]       : 0;
    s[t + 256] = (t + 256 < nb) ? bsum[t + 256] : 0;
    __syncthreads();
    int o0 = s[t], o1 = s[t + 256];
    for (int off = 1; off < MAXB; off <<= 1) {
        int a = (t       >= off) ? s[t       - off] : 0;
        int b = (t + 256 >= off) ? s[t + 256 - off] : 0;
        __syncthreads();
        s[t] += a; s[t + 256] += b;
        __syncthreads();
    }
    if (t       < nb) bsum[t]       = s[t]       - o0;
    if (t + 256 < nb) bsum[t + 256] = s[t + 256] - o1;
}

__global__ void __launch_bounds__(256) scan3_kernel(
    int* __restrict__ data, int M, const int* __restrict__ bsum)
{
    int add = bsum[blockIdx.x];
    if (add == 0) return;
    int i0 = blockIdx.x * EPB + threadIdx.x * 4;
    if (i0 + 3 < M) {
        int4 q = *(const int4*)(data + i0);
        q.x += add; q.y += add; q.z += add; q.w += add;
        *(int4*)(data + i0) = q;
    } else {
        if (i0     < M) data[i0]     += add;
        if (i0 + 1 < M) data[i0 + 1] += add;
        if (i0 + 2 < M) data[i0 + 2] += add;
    }
}

__global__ void __launch_bounds__(256) fill_kernel(
    const int* __restrict__ ei66, const int* __restrict__ ei86,
    const int* __restrict__ ei68, const int* __restrict__ ei88,
    int E66, int E86, int E68, int E88, int N6, int N8,
    int* __restrict__ base, int* __restrict__ csr)
{
    int Etot = E66 + E86 + E68 + E88;
    for (int gid = blockIdx.x * 256 + threadIdx.x; gid < Etot;
         gid += gridDim.x * 256) {
        int le = gid, nb, dst;
        if (le < E66)               { dst = ei66[2 * le + 1]; nb = 0; }
        else if ((le -= E66) < E86) { dst = ei86[2 * le + 1]; nb = N6; }
        else if ((le -= E86) < E68) { dst = ei68[2 * le + 1]; nb = 2 * N6; }
        else { le -= E68;             dst = ei88[2 * le + 1]; nb = 2 * N6 + N8; }
        int pos = atomicAdd(base + nb + dst, 1);
        csr[pos] = gid;
    }
}

// ===========================================================================
// Fused kernel, edge-parallel: per 64-node tile, waves split the tile's
// CONTIGUOUS csr slot range into slot-chunks (perfect balance). Per edge:
// one coalesced 512B float2 load + two parity-staggered ds_add_f32 into a
// shared f32 accumulator tile (2-way bank access = free). Row id is a
// wave-uniform scalar walk. Then MFMA reads A directly from f32 LDS
// (scale by 1/deg, pack bf16 in-register) x bf16 W^T, coalesced store.
// After fill: start(g) = g ? base[g-1] : 0, end(g) = base[g].
// ===========================================================================
__global__ void __launch_bounds__(256, 2) gather_mfma_kernel(
    const float* __restrict__ msg, const float* __restrict__ Wm,
    const int* __restrict__ base, const int* __restrict__ csr,
    int gbase, int ebase, float* __restrict__ out, int N, int ntiles)
{
    __shared__ alignas(16) short Wt[DF * WSTS];    // 34.0 KB bf16 W^T, padded
    __shared__ alignas(16) float Atf[TPB * AST];   // 33.0 KB f32 accum, padded
    __shared__ int ends_s[TPB + 1];

    const int t    = threadIdx.x;
    const int lane = t & 63;
    const int w    = t >> 6;
    const int l15  = lane & 15;
    const int lg   = lane >> 4;

    // ---- stage W^T once per block: Wt[n][k] = bf16(W[k][n]), plain pad ----
    for (int idx = t; idx < 2048; idx += 256) {
        int k0 = (idx >> 5) << 1;        // even k
        int ng = (idx & 31) << 2;        // n group base
        float4 wa = *(const float4*)(Wm + (size_t)k0 * DF + ng);
        float4 wb = *(const float4*)(Wm + (size_t)(k0 + 1) * DF + ng);
        float wav[4] = {wa.x, wa.y, wa.z, wa.w};
        float wbv[4] = {wb.x, wb.y, wb.z, wb.w};
        #pragma unroll
        for (int j = 0; j < 4; ++j)
            *(unsigned*)(Wt + (ng + j) * WSTS + k0) = pack2bf(wav[j], wbv[j]);
    }

    const int par = lane & 1;
    const int cA  = 2 * lane + par;        // parity-staggered lds columns
    const int cB  = 2 * lane + 1 - par;

    for (int tile = blockIdx.x; tile < ntiles; tile += gridDim.x) {
        const int n0 = tile * TPB;
        __syncthreads();    // previous tile fully consumed (and Wt staged)

        // zero accumulator + stage cumulative ends
        for (int i = t; i < TPB * AST / 4; i += 256)
            ((f32x4*)Atf)[i] = (f32x4){0.f, 0.f, 0.f, 0.f};
        if (t <= TPB) {
            int nn = n0 + t - 1;
            if (nn >= N) nn = N - 1;
            int idx = gbase + nn;
            ends_s[t] = (idx >= 0) ? base[idx] : 0;
        }
        __syncthreads();

        // ---------------- edge-parallel gather ----------------
        const int ts0   = rfl(ends_s[0]);
        const int ts1   = rfl(ends_s[TPB]);
        const int total = ts1 - ts0;
        const int ws    = ts0 + ((total * w) >> 2);
        const int we    = ts0 + ((total * (w + 1)) >> 2);

        if (ws < we) {
            // initial row: last row with start <= ws
            int lo = 0, hi = TPB;
            while (hi - lo > 1) {
                int mid = (lo + hi) >> 1;
                if (rfl(ends_s[mid]) <= ws) lo = mid; else hi = mid;
            }
            int row  = lo;
            int rb   = row * AST;
            int nend = rfl(ends_s[row + 1]);

#define LDEID(e, sb) do { _Pragma("unroll")                                   \
            for (int j = 0; j < 8; ++j) {                                     \
                int ii = (sb) + j; ii = (ii < we) ? ii : (we - 1);            \
                e[j] = csr[ii]; } } while (0)

#define LDMSG(v, e, sb) do {                                                  \
            if ((sb) + 8 <= we) { _Pragma("unroll")                           \
                for (int j = 0; j < 8; ++j)                                   \
                    v[j] = *(const float2*)(msg +                             \
                        (size_t)(e[j] - ebase) * DF + 2 * lane);              \
            } else { _Pragma("unroll")                                        \
                for (int j = 0; j < 8; ++j)                                   \
                    v[j] = ((sb) + j < we)                                    \
                        ? *(const float2*)(msg +                              \
                            (size_t)(e[j] - ebase) * DF + 2 * lane)           \
                        : make_float2(0.f, 0.f); } } while (0)

#define CONS(v, sb) do {                                                      \
            if ((sb) + 8 <= we) { _Pragma("unroll")                           \
                for (int j = 0; j < 8; ++j) {                                 \
                    int slot = (sb) + j;                                      \
                    while (slot >= nend) {                                    \
                        ++row; rb += AST;                                     \
                        nend = rfl(ends_s[row + 1]); }                        \
                    atomicAdd(Atf + rb + cA, par ? v[j].y : v[j].x);          \
                    atomicAdd(Atf + rb + cB, par ? v[j].x : v[j].y); }        \
            } else { _Pragma("unroll")                                        \
                for (int j = 0; j < 8; ++j) {                                 \
                    int slot = (sb) + j;                                      \
                    if (slot < we) {                                          \
                        while (slot >= nend) {                                \
                            ++row; rb += AST;                                 \
                            nend = rfl(ends_s[row + 1]); }                    \
                        atomicAdd(Atf + rb + cA, par ? v[j].y : v[j].x);      \
                        atomicAdd(Atf + rb + cB, par ? v[j].x : v[j].y); } } \
            } } while (0)

            int eA[8], eB[8];
            float2 vA[8], vB[8];
            LDEID(eA, ws);
            LDEID(eB, ws + 8);
            LDMSG(vA, eA, ws);

            int b = ws;
            while (b < we) {
                LDMSG(vB, eB, b + 8);
                LDEID(eA, b + 16);
                CONS(vA, b);
                b += 8;
                if (b >= we) break;
                LDMSG(vA, eA, b + 8);
                LDEID(eB, b + 16);
                CONS(vB, b);
                b += 8;
            }
#undef LDEID
#undef LDMSG
#undef CONS
        }
        __syncthreads();

        // ---------------- MFMA: wave's 16 rows x 128 cols ------------------
        // A(m,k): m=lane&15, k=(lane>>4)*8+j ; B(k,n): n=lane&15, same k.
        // D: col=lane&15, row=(lane>>4)*4+reg.
        const int lrow = 16 * w + l15;
        int deg = ends_s[lrow + 1] - ends_s[lrow];
        float inv = (deg > 0) ? (1.0f / (float)deg) : 0.0f;
        const float* ar = Atf + lrow * AST;

        f32x4 acc[8];
        #pragma unroll
        for (int j = 0; j < 8; ++j) acc[j] = (f32x4){0.f, 0.f, 0.f, 0.f};

        #pragma unroll
        for (int kk = 0; kk < 4; ++kk) {
            float4 fa = *(const float4*)(ar + kk * 32 + lg * 8);
            float4 fb = *(const float4*)(ar + kk * 32 + lg * 8 + 4);
            union { unsigned u[4]; short8 s; } av;
            av.u[0] = pack2bf(fa.x * inv, fa.y * inv);
            av.u[1] = pack2bf(fa.z * inv, fa.w * inv);
            av.u[2] = pack2bf(fb.x * inv, fb.y * inv);
            av.u[3] = pack2bf(fb.z * inv, fb.w * inv);
            #pragma unroll
            for (int j = 0; j < 8; ++j) {
                short8 bv = *(const short8*)(Wt + (j * 16 + l15) * WSTS
                                             + kk * 32 + lg * 8);
                acc[j] = __builtin_amdgcn_mfma_f32_16x16x32_bf16(
                    av.s, bv, acc[j], 0, 0, 0);
            }
        }

        // ------------- store: LDS transpose -> coalesced float4 -----------
        float* fA = Atf + (size_t)(16 * w) * AST;   // wave-private scratch
        #pragma unroll
        for (int h = 0; h < 2; ++h) {
            if ((lg >> 1) == h) {
                int lr = (lg & 1) << 2;
                #pragma unroll
                for (int q = 0; q < 4; ++q)
                    #pragma unroll
                    for (int j = 0; j < 8; ++j)
                        fA[(lr + q) * DF + j * 16 + l15] = acc[j][q];
            }
            asm volatile("" ::: "memory");
            #pragma unroll
            for (int rr = 0; rr < 4; ++rr) {
                int lrh  = 2 * rr + (lane >> 5);
                int node = n0 + 16 * w + 8 * h + lrh;
                float4 x = *(const float4*)(fA + lrh * DF + (lane & 31) * 4);
                if (node < N)
                    *(float4*)(out + (size_t)node * 256 + (lane & 31) * 4) = x;
            }
            asm volatile("" ::: "memory");
        }
    }
}

// masks from post-fill base diffs: num_types = (deg_a>0) + (deg_b>0)
__global__ void __launch_bounds__(256) mask_kernel(
    const int* __restrict__ base, float* __restrict__ nt6,
    float* __restrict__ nt8, int N6, int N8)
{
    int i = blockIdx.x * blockDim.x + threadIdx.x;
    if (i < N6) {
        int g66 = i, g86 = N6 + i;
        int d66 = base[g66] - (g66 ? base[g66 - 1] : 0);
        int d86 = base[g86] - base[g86 - 1];
        nt6[i] = (float)((d66 > 0) + (d86 > 0));
    }
    if (i < N8) {
        int g68 = 2 * N6 + i, g88 = 2 * N6 + N8 + i;
        int d68 = base[g68] - base[g68 - 1];
        int d88 = base[g88] - base[g88 - 1];
        nt8[i] = (float)((d68 > 0) + (d88 > 0));
    }
}

extern "C" void kernel_launch(void* const* d_in, const int* in_sizes, int n_in,
                              void* d_out, int out_size, void* d_ws, size_t ws_size,
                              hipStream_t stream)
{
    const float* msg66 = (const float*)d_in[0];
    const float* msg68 = (const float*)d_in[1];
    const float* msg86 = (const float*)d_in[2];
    const float* msg88 = (const float*)d_in[3];
    const float* W66   = (const float*)d_in[4];
    const float* W68   = (const float*)d_in[5];
    const float* W86   = (const float*)d_in[6];
    const float* W88   = (const float*)d_in[7];
    const int*   ei66  = (const int*)d_in[8];
    const int*   ei68  = (const int*)d_in[9];
    const int*   ei86  = (const int*)d_in[10];
    const int*   ei88  = (const int*)d_in[11];

    int E66 = in_sizes[8]  / 2;
    int E68 = in_sizes[9]  / 2;
    int E86 = in_sizes[10] / 2;
    int E88 = in_sizes[11] / 2;
    int Etot = E66 + E86 + E68 + E88;

    size_t S  = (size_t)out_size / 257;       // out = 257*(N6+N8)
    int    N6 = (int)(S / 2);
    int    N8 = (int)(S - S / 2);
    int    M  = 2 * N6 + 2 * N8;

    float* out  = (float*)d_out;
    float* out6 = out;                          // (N6, 2, 128)
    float* out8 = out + (size_t)N6 * 256;       // (N8, 2, 128)
    float* nt6  = out + (size_t)(N6 + N8) * 256;
    float* nt8  = nt6 + N6;

    int* base = (int*)d_ws;                     // [M]
    int* bsum = base + M;                       // [MAXB]
    int* csr  = bsum + MAXB;                    // [Etot]

    int NB = (M + EPB - 1) / EPB;               // scan chunks (M=400K -> 391)

    hipMemsetAsync(base, 0, (size_t)M * sizeof(int), stream);

    int eg = (Etot + 255) / 256;
    if (eg > 4096) eg = 4096;
    count_kernel<<<dim3(eg), dim3(256), 0, stream>>>(
        ei66, ei86, ei68, ei88, E66, E86, E68, E88, N6, N8, base);

    scan1_kernel<<<dim3(NB), dim3(256), 0, stream>>>(base, M, bsum);
    scan2_kernel<<<dim3(1),  dim3(256), 0, stream>>>(bsum, NB);
    scan3_kernel<<<dim3(NB), dim3(256), 0, stream>>>(base, M, bsum);

    fill_kernel<<<dim3(eg), dim3(256), 0, stream>>>(
        ei66, ei86, ei68, ei88, E66, E86, E68, E88, N6, N8, base, csr);

    int eb66 = 0, eb86 = E66, eb68 = E66 + E86, eb88 = E66 + E86 + E68;

    int t6 = (N6 + TPB - 1) / TPB, t8 = (N8 + TPB - 1) / TPB;
    dim3 b(256), g6((t6 + 1) / 2), g8((t8 + 1) / 2);   // ~2 tiles per block
    gather_mfma_kernel<<<g6, b, 0, stream>>>(msg66, W66, base, csr, 0,           eb66, out6,       N6, t6);
    gather_mfma_kernel<<<g6, b, 0, stream>>>(msg86, W86, base, csr, N6,          eb86, out6 + 128, N6, t6);
    gather_mfma_kernel<<<g8, b, 0, stream>>>(msg68, W68, base, csr, 2 * N6,      eb68, out8,       N8, t8);
    gather_mfma_kernel<<<g8, b, 0, stream>>>(msg88, W88, base, csr, 2 * N6 + N8, eb88, out8 + 128, N8, t8);

    int Nmax = (N6 > N8) ? N6 : N8;
    mask_kernel<<<dim3((Nmax + 255) / 256), dim3(256), 0, stream>>>(
        base, nt6, nt8, N6, N8);
}

// Round 9
// 477.803 us; speedup vs baseline: 3.4696x; 3.4696x over previous
//
#include <hip/hip_runtime.h>

#define DF    128   // feature dim
#define EPB   1024  // elements per scan block
#define MAXB  512   // max level-2 scan width (supports M <= 524288)
#define TPB   64    // nodes per block-tile
#define ATS   132   // At row stride in shorts (128 + 4)
#define WSTS  136   // Wt row stride in shorts (128 + 8)
#define CAP   512   // staged edge-ids per tile (mean ~256, sigma ~16)

typedef __attribute__((ext_vector_type(8))) short short8;
typedef __attribute__((ext_vector_type(4))) float f32x4;

__device__ __forceinline__ unsigned short f2bf(float x) {
    unsigned u = __float_as_uint(x);
    u = (u + 0x7FFFu + ((u >> 16) & 1u)) >> 16;   // RNE
    return (unsigned short)u;
}
__device__ __forceinline__ unsigned pack2bf(float a, float b) {
    return (unsigned)f2bf(a) | ((unsigned)f2bf(b) << 16);
}
__device__ __forceinline__ int rfl(int x) {
    return __builtin_amdgcn_readfirstlane(x);
}

struct AllParams {
    const float* msg[4];
    const float* Wm[4];
    float*       outp[4];
    int gb[4];
    int eb[4];
    int N[4];
    int cum[5];    // cumulative tile counts; cum[4] = total tiles
};

// ===========================================================================
// CSR build: count degrees -> exclusive scan -> place edge ids (row-packed).
// Node space M = [66: 0..N6) [86: N6..2N6) [68: 2N6..2N6+N8) [88: ...+N8)
// Edge space  = [66: 0..E66) [86 ...) [68 ...) [88 ...)  (global gid)
// csr entry = gid | (dst & 63) << 26   (tile-local row in high 6 bits)
// ===========================================================================

__global__ void __launch_bounds__(256) count_kernel(
    const int* __restrict__ ei66, const int* __restrict__ ei86,
    const int* __restrict__ ei68, const int* __restrict__ ei88,
    int E66, int E86, int E68, int E88, int N6, int N8,
    int* __restrict__ base)
{
    int Etot = E66 + E86 + E68 + E88;
    for (int gid = blockIdx.x * 256 + threadIdx.x; gid < Etot;
         gid += gridDim.x * 256) {
        int le = gid, nb, dst;
        if (le < E66)               { dst = ei66[2 * le + 1]; nb = 0; }
        else if ((le -= E66) < E86) { dst = ei86[2 * le + 1]; nb = N6; }
        else if ((le -= E86) < E68) { dst = ei68[2 * le + 1]; nb = 2 * N6; }
        else { le -= E68;             dst = ei88[2 * le + 1]; nb = 2 * N6 + N8; }
        atomicAdd(base + nb + dst, 1);
    }
}

__global__ void __launch_bounds__(256) scan1_kernel(
    int* __restrict__ data, int M, int* __restrict__ bsum)
{
    __shared__ int ts[256];
    int t = threadIdx.x;
    int i0 = blockIdx.x * EPB + t * 4;
    int v0 = 0, v1 = 0, v2 = 0, v3 = 0;
    if (i0 + 3 < M) {
        int4 q = *(const int4*)(data + i0);
        v0 = q.x; v1 = q.y; v2 = q.z; v3 = q.w;
    } else {
        if (i0     < M) v0 = data[i0];
        if (i0 + 1 < M) v1 = data[i0 + 1];
        if (i0 + 2 < M) v2 = data[i0 + 2];
    }
    int sum = v0 + v1 + v2 + v3;
    ts[t] = sum;
    __syncthreads();
    for (int off = 1; off < 256; off <<= 1) {
        int x = (t >= off) ? ts[t - off] : 0;
        __syncthreads();
        ts[t] += x;
        __syncthreads();
    }
    int excl = ts[t] - sum;
    if (t == 255) bsum[blockIdx.x] = ts[255];
    int w0 = excl, w1 = excl + v0, w2 = w1 + v1, w3 = w2 + v2;
    if (i0 + 3 < M) {
        *(int4*)(data + i0) = make_int4(w0, w1, w2, w3);
    } else {
        if (i0     < M) data[i0]     = w0;
        if (i0 + 1 < M) data[i0 + 1] = w1;
        if (i0 + 2 < M) data[i0 + 2] = w2;
    }
}

__global__ void __launch_bounds__(256) scan2_kernel(int* __restrict__ bsum, int nb)
{
    __shared__ int s[MAXB];
    int t = threadIdx.x;
    s[t]       = (t       < nb) ? bsum[t]       : 0;
    s[t + 256] = (t + 256 < nb) ? bsum[t + 256] : 0;
    __syncthreads();
    int o0 = s[t], o1 = s[t + 256];
    for (int off = 1; off < MAXB; off <<= 1) {
        int a = (t       >= off) ? s[t       - off] : 0;
        int b = (t + 256 >= off) ? s[t + 256 - off] : 0;
        __syncthreads();
        s[t] += a; s[t + 256] += b;
        __syncthreads();
    }
    if (t       < nb) bsum[t]       = s[t]       - o0;
    if (t + 256 < nb) bsum[t + 256] = s[t + 256] - o1;
}

__global__ void __launch_bounds__(256) scan3_kernel(
    int* __restrict__ data, int M, const int* __restrict__ bsum)
{
    int add = bsum[blockIdx.x];
    if (add == 0) return;
    int i0 = blockIdx.x * EPB + threadIdx.x * 4;
    if (i0 + 3 < M) {
        int4 q = *(const int4*)(data + i0);
        q.x += add; q.y += add; q.z += add; q.w += add;
        *(int4*)(data + i0) = q;
    } else {
        if (i0     < M) data[i0]     += add;
        if (i0 + 1 < M) data[i0 + 1] += add;
        if (i0 + 2 < M) data[i0 + 2] += add;
    }
}

__global__ void __launch_bounds__(256) fill_kernel(
    const int* __restrict__ ei66, const int* __restrict__ ei86,
    const int* __restrict__ ei68, const int* __restrict__ ei88,
    int E66, int E86, int E68, int E88, int N6, int N8,
    int* __restrict__ base, int* __restrict__ csr)
{
    int Etot = E66 + E86 + E68 + E88;
    for (int gid = blockIdx.x * 256 + threadIdx.x; gid < Etot;
         gid += gridDim.x * 256) {
        int le = gid, nb, dst;
        if (le < E66)               { dst = ei66[2 * le + 1]; nb = 0; }
        else if ((le -= E66) < E86) { dst = ei86[2 * le + 1]; nb = N6; }
        else if ((le -= E86) < E68) { dst = ei68[2 * le + 1]; nb = 2 * N6; }
        else { le -= E68;             dst = ei88[2 * le + 1]; nb = 2 * N6 + N8; }
        int pos = atomicAdd(base + nb + dst, 1);
        csr[pos] = (int)((unsigned)gid | (((unsigned)(dst & 63)) << 26));
    }
}

// ===========================================================================
// Fused kernel, all 4 types in one dispatch. Per 64-node tile:
//  - stage tile's edge ids (csr slice) into LDS (coalesced, ~256 ints)
//  - per wave (16 rows): flat slot walk, depth-3 msg pipeline (ids from LDS,
//    so consume of batch i drains only batch i's msg loads -> 2 batches
//    always in flight), row boundaries from packed high bits, bf16 flush
//  - MFMA 16x128 from LDS A-tile x bf16 W^T, mean applied to f32 acc
//  - coalesced float4 store via LDS transpose
// ===========================================================================
__global__ void __launch_bounds__(256, 3) gather_mfma_kernel(
    const int* __restrict__ base, const int* __restrict__ csr, AllParams P)
{
    __shared__ alignas(16) short Wt[DF * WSTS];     // 34.0 KB
    __shared__ alignas(16) short At[4][16 * ATS];   // 16.5 KB
    __shared__ int eids[CAP];                       //  2.0 KB
    __shared__ int ends_s[TPB + 1];

    const int t    = threadIdx.x;
    const int lane = t & 63;
    const int w    = t >> 6;
    const int l15  = lane & 15;
    const int lg   = lane >> 4;
    short* Atw = At[w];

    int curty = -1;
    const int T = P.cum[4];

    for (int tt = blockIdx.x * 2; tt < blockIdx.x * 2 + 2 && tt < T; ++tt) {
        const int ty = (tt >= P.cum[2]) ? ((tt >= P.cum[3]) ? 3 : 2)
                                        : ((tt >= P.cum[1]) ? 1 : 0);
        const float* msg = P.msg[ty];
        const int gbase = P.gb[ty], ebase = P.eb[ty], N = P.N[ty];
        const int n0 = (tt - P.cum[ty]) * TPB;

        __syncthreads();   // previous tile fully consumed (eids/ends/Wt)

        if (ty != curty) {     // stage W^T bf16: Wt[n][k] = bf16(W[k][n])
            const float* Wm = P.Wm[ty];
            for (int idx = t; idx < 2048; idx += 256) {
                int k0 = (idx >> 5) << 1;
                int ng = (idx & 31) << 2;
                float4 wa = *(const float4*)(Wm + (size_t)k0 * DF + ng);
                float4 wb = *(const float4*)(Wm + (size_t)(k0 + 1) * DF + ng);
                float wav[4] = {wa.x, wa.y, wa.z, wa.w};
                float wbv[4] = {wb.x, wb.y, wb.z, wb.w};
                #pragma unroll
                for (int j = 0; j < 4; ++j)
                    *(unsigned*)(Wt + (ng + j) * WSTS + k0) =
                        pack2bf(wav[j], wbv[j]);
            }
            curty = ty;
        }

        if (t <= TPB) {        // cumulative ends for rows -1..63
            int nn = n0 + t - 1;
            if (nn >= N) nn = N - 1;
            int gi = gbase + nn;
            ends_s[t] = (gi >= 0) ? base[gi] : 0;
        }
        {                      // stage edge ids (self-computed bounds)
            int gi0   = gbase + n0 - 1;
            int myts0 = (gi0 >= 0) ? base[gi0] : 0;
            int nn = n0 + TPB - 1; if (nn >= N) nn = N - 1;
            int myts1 = base[gbase + nn];
            int tot_all = myts1 - myts0;
            for (int i = t; i < tot_all && i < CAP; i += 256)
                eids[i] = csr[myts0 + i];
        }
        __syncthreads();

        const int ts0   = ends_s[0];
        const int wrow0 = w * 16;
        const int s0    = ends_s[wrow0];
        const int s1    = ends_s[wrow0 + 16];
        const int lbase = s0 - ts0;
        const int tot   = s1 - s0;
        int   cur = wrow0;
        float ax = 0.f, ay = 0.f;

#define LDE(eX, sb) { _Pragma("unroll")                                       \
        for (int j = 0; j < 8; ++j) {                                         \
            int ls = (sb) + j; ls = (ls < tot) ? ls : (tot - 1);              \
            int gs = lbase + ls;                                              \
            eX[j] = (gs < CAP) ? eids[gs] : csr[ts0 + gs]; } }

#define LDM(vX, eX) { _Pragma("unroll")                                       \
        for (int j = 0; j < 8; ++j) {                                         \
            int idx = (int)(((unsigned)eX[j]) & 0x03FFFFFFu) - ebase;         \
            vX[j] = *(const float2*)(msg + (size_t)idx * DF + 2 * lane); } }

#define FLUSHR() {                                                            \
        *(unsigned*)(Atw + (cur & 15) * ATS + 2 * lane) = pack2bf(ax, ay);    \
        ax = 0.f; ay = 0.f; ++cur; }

#define CONSB(vX, eX, sb) { _Pragma("unroll")                                 \
        for (int j = 0; j < 8; ++j) {                                         \
            if ((sb) + j < tot) {                                             \
                int rl = (int)(((unsigned)rfl(eX[j])) >> 26);                 \
                while (cur < rl) FLUSHR();                                    \
                ax += vX[j].x; ay += vX[j].y; } } }

        if (tot > 0) {
            int eA[8], eB[8], eC[8];
            float2 vA[8], vB[8], vC[8];
            const int nb = (tot + 7) >> 3;

            LDE(eA, 0); LDE(eB, 8);
            LDM(vA, eA); LDM(vB, eB);
            int ib = 0;
            while (true) {
                LDE(eC, ib * 8 + 16); LDM(vC, eC); CONSB(vA, eA, ib * 8);
                if (++ib >= nb) break;
                LDE(eA, ib * 8 + 16); LDM(vA, eA); CONSB(vB, eB, ib * 8);
                if (++ib >= nb) break;
                LDE(eB, ib * 8 + 16); LDM(vB, eB); CONSB(vC, eC, ib * 8);
                if (++ib >= nb) break;
            }
        }
        while (cur < wrow0 + 16) FLUSHR();
#undef LDE
#undef LDM
#undef FLUSHR
#undef CONSB

        // ---------------- MFMA: wave's 16 rows x 128 cols ------------------
        // A(m,k): m=lane&15, k=32*kk+8*lg+j ; B(k,n): n=lane&15, same k.
        // D: col=lane&15, row=lg*4+reg.
        f32x4 acc[8];
        #pragma unroll
        for (int j = 0; j < 8; ++j) acc[j] = (f32x4){0.f, 0.f, 0.f, 0.f};

        #pragma unroll
        for (int kk = 0; kk < 4; ++kk) {
            short8 av = *(const short8*)(Atw + l15 * ATS + kk * 32 + lg * 8);
            #pragma unroll
            for (int j = 0; j < 8; ++j) {
                short8 bv = *(const short8*)(Wt + (j * 16 + l15) * WSTS
                                             + kk * 32 + lg * 8);
                acc[j] = __builtin_amdgcn_mfma_f32_16x16x32_bf16(
                    av, bv, acc[j], 0, 0, 0);
            }
        }

        // mean (exact commutation: (sum@W)/deg == (sum/deg)@W in math;
        // bf16 error unchanged vs r7, absmax 0.031 << 0.111)
        #pragma unroll
        for (int q = 0; q < 4; ++q) {
            int lrow = wrow0 + lg * 4 + q;
            int dg = ends_s[lrow + 1] - ends_s[lrow];
            float inv = (dg > 0) ? (1.0f / (float)dg) : 0.0f;
            #pragma unroll
            for (int j = 0; j < 8; ++j) acc[j][q] *= inv;
        }

        // ------------- store: LDS transpose -> coalesced float4 -----------
        float* fA = (float*)Atw;           // wave-private scratch (4224B)
        float* outp = P.outp[ty];
        #pragma unroll
        for (int h = 0; h < 2; ++h) {
            if ((lg >> 1) == h) {
                int lr = (lg & 1) << 2;
                #pragma unroll
                for (int q = 0; q < 4; ++q)
                    #pragma unroll
                    for (int j = 0; j < 8; ++j)
                        fA[(lr + q) * DF + j * 16 + l15] = acc[j][q];
            }
            asm volatile("" ::: "memory");
            #pragma unroll
            for (int rr = 0; rr < 4; ++rr) {
                int lrh  = 2 * rr + (lane >> 5);
                int node = n0 + wrow0 + 8 * h + lrh;
                float4 x = *(const float4*)(fA + lrh * DF + (lane & 31) * 4);
                if (node < N)
                    *(float4*)(outp + (size_t)node * 256 + (lane & 31) * 4) = x;
            }
            asm volatile("" ::: "memory");
        }
    }
}

// masks from post-fill base diffs: num_types = (deg_a>0) + (deg_b>0)
__global__ void __launch_bounds__(256) mask_kernel(
    const int* __restrict__ base, float* __restrict__ nt6,
    float* __restrict__ nt8, int N6, int N8)
{
    int i = blockIdx.x * blockDim.x + threadIdx.x;
    if (i < N6) {
        int g66 = i, g86 = N6 + i;
        int d66 = base[g66] - (g66 ? base[g66 - 1] : 0);
        int d86 = base[g86] - base[g86 - 1];
        nt6[i] = (float)((d66 > 0) + (d86 > 0));
    }
    if (i < N8) {
        int g68 = 2 * N6 + i, g88 = 2 * N6 + N8 + i;
        int d68 = base[g68] - base[g68 - 1];
        int d88 = base[g88] - base[g88 - 1];
        nt8[i] = (float)((d68 > 0) + (d88 > 0));
    }
}

extern "C" void kernel_launch(void* const* d_in, const int* in_sizes, int n_in,
                              void* d_out, int out_size, void* d_ws, size_t ws_size,
                              hipStream_t stream)
{
    const float* msg66 = (const float*)d_in[0];
    const float* msg68 = (const float*)d_in[1];
    const float* msg86 = (const float*)d_in[2];
    const float* msg88 = (const float*)d_in[3];
    const float* W66   = (const float*)d_in[4];
    const float* W68   = (const float*)d_in[5];
    const float* W86   = (const float*)d_in[6];
    const float* W88   = (const float*)d_in[7];
    const int*   ei66  = (const int*)d_in[8];
    const int*   ei68  = (const int*)d_in[9];
    const int*   ei86  = (const int*)d_in[10];
    const int*   ei88  = (const int*)d_in[11];

    int E66 = in_sizes[8]  / 2;
    int E68 = in_sizes[9]  / 2;
    int E86 = in_sizes[10] / 2;
    int E88 = in_sizes[11] / 2;
    int Etot = E66 + E86 + E68 + E88;

    size_t S  = (size_t)out_size / 257;       // out = 257*(N6+N8)
    int    N6 = (int)(S / 2);
    int    N8 = (int)(S - S / 2);
    int    M  = 2 * N6 + 2 * N8;

    float* out  = (float*)d_out;
    float* out6 = out;                          // (N6, 2, 128)
    float* out8 = out + (size_t)N6 * 256;       // (N8, 2, 128)
    float* nt6  = out + (size_t)(N6 + N8) * 256;
    float* nt8  = nt6 + N6;

    int* base = (int*)d_ws;                     // [M]
    int* bsum = base + M;                       // [MAXB]
    int* csr  = bsum + MAXB;                    // [Etot]

    int NB = (M + EPB - 1) / EPB;               // scan chunks (M=400K -> 391)

    hipMemsetAsync(base, 0, (size_t)M * sizeof(int), stream);

    int eg = (Etot + 255) / 256;
    if (eg > 4096) eg = 4096;
    count_kernel<<<dim3(eg), dim3(256), 0, stream>>>(
        ei66, ei86, ei68, ei88, E66, E86, E68, E88, N6, N8, base);

    scan1_kernel<<<dim3(NB), dim3(256), 0, stream>>>(base, M, bsum);
    scan2_kernel<<<dim3(1),  dim3(256), 0, stream>>>(bsum, NB);
    scan3_kernel<<<dim3(NB), dim3(256), 0, stream>>>(base, M, bsum);

    fill_kernel<<<dim3(eg), dim3(256), 0, stream>>>(
        ei66, ei86, ei68, ei88, E66, E86, E68, E88, N6, N8, base, csr);

    int t6 = (N6 + TPB - 1) / TPB, t8 = (N8 + TPB - 1) / TPB;
    AllParams P;
    P.msg[0] = msg66; P.Wm[0] = W66; P.outp[0] = out6;       P.gb[0] = 0;           P.eb[0] = 0;                P.N[0] = N6;
    P.msg[1] = msg86; P.Wm[1] = W86; P.outp[1] = out6 + 128; P.gb[1] = N6;          P.eb[1] = E66;              P.N[1] = N6;
    P.msg[2] = msg68; P.Wm[2] = W68; P.outp[2] = out8;       P.gb[2] = 2 * N6;      P.eb[2] = E66 + E86;        P.N[2] = N8;
    P.msg[3] = msg88; P.Wm[3] = W88; P.outp[3] = out8 + 128; P.gb[3] = 2 * N6 + N8; P.eb[3] = E66 + E86 + E68;  P.N[3] = N8;
    P.cum[0] = 0;
    P.cum[1] = t6;
    P.cum[2] = 2 * t6;
    P.cum[3] = 2 * t6 + t8;
    P.cum[4] = 2 * t6 + 2 * t8;

    int G = (P.cum[4] + 1) / 2;                 // 2 tiles per block
    gather_mfma_kernel<<<dim3(G), dim3(256), 0, stream>>>(base, csr, P);

    int Nmax = (N6 > N8) ? N6 : N8;
    mask_kernel<<<dim3((Nmax + 255) / 256), dim3(256), 0, stream>>>(
        base, nt6, nt8, N6, N8);
}

// Round 10
// 458.671 us; speedup vs baseline: 3.6143x; 1.0417x over previous
//
#include <hip/hip_runtime.h>

#define DF    128   // feature dim
#define EPB   1024  // elements per scan block
#define MAXB  512   // max level-2 scan width (supports M <= 524288)
#define TPB   64    // nodes per block-tile
#define CAP   512   // staged edge-ids per tile (mean ~256)

typedef __attribute__((ext_vector_type(8))) short short8;
typedef __attribute__((ext_vector_type(4))) float f32x4;

__device__ __forceinline__ unsigned short f2bf(float x) {
    unsigned u = __float_as_uint(x);
    u = (u + 0x7FFFu + ((u >> 16) & 1u)) >> 16;   // RNE
    return (unsigned short)u;
}
__device__ __forceinline__ unsigned pack2bf(float a, float b) {
    return (unsigned)f2bf(a) | ((unsigned)f2bf(b) << 16);
}
__device__ __forceinline__ int rfl(int x) {
    return __builtin_amdgcn_readfirstlane(x);
}

struct AllParams {
    const float* msg[4];
    const float* Wm[4];
    float*       outp[4];
    int gb[4];
    int eb[4];
    int N[4];
    int cum[5];    // cumulative tile counts; cum[4] = total tiles
};

// ===========================================================================
// CSR build: count degrees -> exclusive scan -> place edge ids (row-packed).
// csr entry = gid | (dst & 63) << 26   (tile-local row in high 6 bits)
// ===========================================================================

__global__ void __launch_bounds__(256) count_kernel(
    const int* __restrict__ ei66, const int* __restrict__ ei86,
    const int* __restrict__ ei68, const int* __restrict__ ei88,
    int E66, int E86, int E68, int E88, int N6, int N8,
    int* __restrict__ base)
{
    int Etot = E66 + E86 + E68 + E88;
    for (int gid = blockIdx.x * 256 + threadIdx.x; gid < Etot;
         gid += gridDim.x * 256) {
        int le = gid, nb, dst;
        if (le < E66)               { dst = ei66[2 * le + 1]; nb = 0; }
        else if ((le -= E66) < E86) { dst = ei86[2 * le + 1]; nb = N6; }
        else if ((le -= E86) < E68) { dst = ei68[2 * le + 1]; nb = 2 * N6; }
        else { le -= E68;             dst = ei88[2 * le + 1]; nb = 2 * N6 + N8; }
        atomicAdd(base + nb + dst, 1);
    }
}

__global__ void __launch_bounds__(256) scan1_kernel(
    int* __restrict__ data, int M, int* __restrict__ bsum)
{
    __shared__ int ts[256];
    int t = threadIdx.x;
    int i0 = blockIdx.x * EPB + t * 4;
    int v0 = 0, v1 = 0, v2 = 0, v3 = 0;
    if (i0 + 3 < M) {
        int4 q = *(const int4*)(data + i0);
        v0 = q.x; v1 = q.y; v2 = q.z; v3 = q.w;
    } else {
        if (i0     < M) v0 = data[i0];
        if (i0 + 1 < M) v1 = data[i0 + 1];
        if (i0 + 2 < M) v2 = data[i0 + 2];
    }
    int sum = v0 + v1 + v2 + v3;
    ts[t] = sum;
    __syncthreads();
    for (int off = 1; off < 256; off <<= 1) {
        int x = (t >= off) ? ts[t - off] : 0;
        __syncthreads();
        ts[t] += x;
        __syncthreads();
    }
    int excl = ts[t] - sum;
    if (t == 255) bsum[blockIdx.x] = ts[255];
    int w0 = excl, w1 = excl + v0, w2 = w1 + v1, w3 = w2 + v2;
    if (i0 + 3 < M) {
        *(int4*)(data + i0) = make_int4(w0, w1, w2, w3);
    } else {
        if (i0     < M) data[i0]     = w0;
        if (i0 + 1 < M) data[i0 + 1] = w1;
        if (i0 + 2 < M) data[i0 + 2] = w2;
    }
}

__global__ void __launch_bounds__(256) scan2_kernel(int* __restrict__ bsum, int nb)
{
    __shared__ int s[MAXB];
    int t = threadIdx.x;
    s[t]       = (t       < nb) ? bsum[t]       : 0;
    s[t + 256] = (t + 256 < nb) ? bsum[t + 256] : 0;
    __syncthreads();
    int o0 = s[t], o1 = s[t + 256];
    for (int off = 1; off < MAXB; off <<= 1) {
        int a = (t       >= off) ? s[t       - off] : 0;
        int b = (t + 256 >= off) ? s[t + 256 - off] : 0;
        __syncthreads();
        s[t] += a; s[t + 256] += b;
        __syncthreads();
    }
    if (t       < nb) bsum[t]       = s[t]       - o0;
    if (t + 256 < nb) bsum[t + 256] = s[t + 256] - o1;
}

__global__ void __launch_bounds__(256) scan3_kernel(
    int* __restrict__ data, int M, const int* __restrict__ bsum)
{
    int add = bsum[blockIdx.x];
    if (add == 0) return;
    int i0 = blockIdx.x * EPB + threadIdx.x * 4;
    if (i0 + 3 < M) {
        int4 q = *(const int4*)(data + i0);
        q.x += add; q.y += add; q.z += add; q.w += add;
        *(int4*)(data + i0) = q;
    } else {
        if (i0     < M) data[i0]     += add;
        if (i0 + 1 < M) data[i0 + 1] += add;
        if (i0 + 2 < M) data[i0 + 2] += add;
    }
}

__global__ void __launch_bounds__(256) fill_kernel(
    const int* __restrict__ ei66, const int* __restrict__ ei86,
    const int* __restrict__ ei68, const int* __restrict__ ei88,
    int E66, int E86, int E68, int E88, int N6, int N8,
    int* __restrict__ base, int* __restrict__ csr)
{
    int Etot = E66 + E86 + E68 + E88;
    for (int gid = blockIdx.x * 256 + threadIdx.x; gid < Etot;
         gid += gridDim.x * 256) {
        int le = gid, nb, dst;
        if (le < E66)               { dst = ei66[2 * le + 1]; nb = 0; }
        else if ((le -= E66) < E86) { dst = ei86[2 * le + 1]; nb = N6; }
        else if ((le -= E86) < E68) { dst = ei68[2 * le + 1]; nb = 2 * N6; }
        else { le -= E68;             dst = ei88[2 * le + 1]; nb = 2 * N6 + N8; }
        int pos = atomicAdd(base + nb + dst, 1);
        csr[pos] = (int)((unsigned)gid | (((unsigned)(dst & 63)) << 26));
    }
}

// ===========================================================================
// Fused kernel, all 4 types in one dispatch. Per 64-node tile:
//  - stage tile's edge ids into LDS (coalesced)
//  - per wave (16 rows): flat slot walk, 4-buffer rotation (3 msg batches in
//    flight), row boundaries from packed high bits, swizzled bf16 flush
//  - MFMA 16x128 from swizzled LDS A-tile x swizzled bf16 W^T, mean on f32
//  - coalesced float4 store via LDS transpose
// LDS swizzle (r6-proven): element k of row m at short idx
//   m*128 + (((k>>3) ^ (m&7))<<3) + (k&7)   -- 16B-aligned b128, <=2-way banks
// ===========================================================================
__global__ void __launch_bounds__(256, 3) gather_mfma_kernel(
    const int* __restrict__ base, const int* __restrict__ csr, AllParams P)
{
    __shared__ alignas(16) short Wt[DF * DF];       // 32 KB, swizzled W^T
    __shared__ alignas(16) short At[4][16 * DF];    // 16 KB, swizzled A-tiles
    __shared__ int eids[CAP];                       //  2 KB
    __shared__ int ends_s[TPB + 1];

    const int t    = threadIdx.x;
    const int lane = t & 63;
    const int w    = t >> 6;
    const int l15  = lane & 15;
    const int lg   = lane >> 4;
    short* Atw = At[w];

    int curty = -1;
    const int T = P.cum[4];

    for (int tt = blockIdx.x * 2; tt < blockIdx.x * 2 + 2 && tt < T; ++tt) {
        const int ty = (tt >= P.cum[2]) ? ((tt >= P.cum[3]) ? 3 : 2)
                                        : ((tt >= P.cum[1]) ? 1 : 0);
        const float* msg = P.msg[ty];
        const int gbase = P.gb[ty], ebase = P.eb[ty], N = P.N[ty];
        const int n0 = (tt - P.cum[ty]) * TPB;

        __syncthreads();   // previous tile fully consumed (eids/ends/Wt)

        if (ty != curty) {     // stage swizzled bf16 W^T (r6-proven layout)
            const float* Wm = P.Wm[ty];
            for (int idx = t; idx < 2048; idx += 256) {
                int k0 = (idx >> 5) << 1;        // even k
                int ng = (idx & 31) << 2;        // n group base
                float4 wa = *(const float4*)(Wm + (size_t)k0 * DF + ng);
                float4 wb = *(const float4*)(Wm + (size_t)(k0 + 1) * DF + ng);
                float wav[4] = {wa.x, wa.y, wa.z, wa.w};
                float wbv[4] = {wb.x, wb.y, wb.z, wb.w};
                int cb = k0 >> 3, kl = k0 & 7;
                #pragma unroll
                for (int j = 0; j < 4; ++j) {
                    int n = ng + j;
                    int chunk = cb ^ (n & 7);
                    *(unsigned*)(Wt + n * DF + chunk * 8 + kl) =
                        pack2bf(wav[j], wbv[j]);
                }
            }
            curty = ty;
        }

        if (t <= TPB) {        // cumulative ends for rows -1..63
            int nn = n0 + t - 1;
            if (nn >= N) nn = N - 1;
            int gi = gbase + nn;
            ends_s[t] = (gi >= 0) ? base[gi] : 0;
        }
        {                      // stage edge ids (self-computed bounds)
            int gi0   = gbase + n0 - 1;
            int myts0 = (gi0 >= 0) ? base[gi0] : 0;
            int nn = n0 + TPB - 1; if (nn >= N) nn = N - 1;
            int myts1 = base[gbase + nn];
            int tot_all = myts1 - myts0;
            for (int i = t; i < tot_all && i < CAP; i += 256)
                eids[i] = csr[myts0 + i];
        }
        __syncthreads();

        const int ts0   = ends_s[0];
        const int wrow0 = w * 16;
        const int s0    = ends_s[wrow0];
        const int s1    = ends_s[wrow0 + 16];
        const int lbase = s0 - ts0;
        const int tot   = s1 - s0;
        int   cur = wrow0;
        float ax = 0.f, ay = 0.f;

#define LDE(eX, sb) { _Pragma("unroll")                                       \
        for (int j = 0; j < 8; ++j) {                                         \
            int ls = (sb) + j; ls = (ls < tot) ? ls : (tot - 1);              \
            int gs = lbase + ls;                                              \
            eX[j] = (gs < CAP) ? eids[gs] : csr[ts0 + gs]; } }

#define LDM(vX, eX) { _Pragma("unroll")                                       \
        for (int j = 0; j < 8; ++j) {                                         \
            int idx = (int)(((unsigned)eX[j]) & 0x03FFFFFFu) - ebase;         \
            vX[j] = *(const float2*)(msg + (size_t)idx * DF + 2 * lane); } }

        // flush row `cur` (local row lr = cur&15): feature pair (2l,2l+1),
        // original chunk = lane>>2, swizzled pos = (lane>>2)^(lr&7)
#define FLUSHR() {                                                            \
        int lr_ = cur & 15;                                                   \
        *(unsigned*)(Atw + lr_ * DF + ((((lane >> 2) ^ (lr_ & 7))) << 3)      \
                     + ((lane & 3) << 1)) = pack2bf(ax, ay);                  \
        ax = 0.f; ay = 0.f; ++cur; }

#define CONSB(vX, eX, sb) { _Pragma("unroll")                                 \
        for (int j = 0; j < 8; ++j) {                                         \
            if ((sb) + j < tot) {                                             \
                int rl = wrow0 + (int)((((unsigned)rfl(eX[j])) >> 26) & 15u); \
                while (cur < rl) FLUSHR();                                    \
                ax += vX[j].x; ay += vX[j].y; } } }

        if (tot > 0) {
            int eA[8], eB[8], eC[8], eD[8];
            float2 vA[8], vB[8], vC[8], vD[8];
            const int nb = (tot + 7) >> 3;

            LDE(eA, 0); LDE(eB, 8); LDE(eC, 16);
            LDM(vA, eA); LDM(vB, eB); LDM(vC, eC);
            int ib = 0;
            while (true) {
                LDE(eD, ib * 8 + 24); LDM(vD, eD); CONSB(vA, eA, ib * 8);
                if (++ib >= nb) break;
                LDE(eA, ib * 8 + 24); LDM(vA, eA); CONSB(vB, eB, ib * 8);
                if (++ib >= nb) break;
                LDE(eB, ib * 8 + 24); LDM(vB, eB); CONSB(vC, eC, ib * 8);
                if (++ib >= nb) break;
                LDE(eC, ib * 8 + 24); LDM(vC, eC); CONSB(vD, eD, ib * 8);
                if (++ib >= nb) break;
            }
        }
        while (cur < wrow0 + 16) FLUSHR();
#undef LDE
#undef LDM
#undef FLUSHR
#undef CONSB

        // ---------------- MFMA: wave's 16 rows x 128 cols ------------------
        // A(m,k): m=lane&15, k=32*kk+8*lg+j ; B(k,n): n=lane&15, same k.
        // D: col=lane&15, row=lg*4+reg.  Swizzled chunk reads (r6-proven).
        f32x4 acc[8];
        #pragma unroll
        for (int j = 0; j < 8; ++j) acc[j] = (f32x4){0.f, 0.f, 0.f, 0.f};

        #pragma unroll
        for (int kk = 0; kk < 4; ++kk) {
            int c = kk * 4 + lg;
            short8 av = *(const short8*)(Atw + l15 * DF
                                         + ((c ^ (l15 & 7)) << 3));
            #pragma unroll
            for (int j = 0; j < 8; ++j) {
                int n = j * 16 + l15;
                short8 bv = *(const short8*)(Wt + n * DF + ((c ^ (n & 7)) << 3));
                acc[j] = __builtin_amdgcn_mfma_f32_16x16x32_bf16(
                    av, bv, acc[j], 0, 0, 0);
            }
        }

        // mean on f32 accumulators ((sum@W)/deg == (sum/deg)@W)
        #pragma unroll
        for (int q = 0; q < 4; ++q) {
            int lrow = wrow0 + lg * 4 + q;
            int dg = ends_s[lrow + 1] - ends_s[lrow];
            float inv = (dg > 0) ? (1.0f / (float)dg) : 0.0f;
            #pragma unroll
            for (int j = 0; j < 8; ++j) acc[j][q] *= inv;
        }

        // ------------- store: LDS transpose -> coalesced float4 -----------
        float* fA = (float*)Atw;           // wave-private scratch (4096B)
        float* outp = P.outp[ty];
        #pragma unroll
        for (int h = 0; h < 2; ++h) {
            if ((lg >> 1) == h) {
                int lr = (lg & 1) << 2;
                #pragma unroll
                for (int q = 0; q < 4; ++q)
                    #pragma unroll
                    for (int j = 0; j < 8; ++j)
                        fA[(lr + q) * DF + j * 16 + l15] = acc[j][q];
            }
            asm volatile("" ::: "memory");
            #pragma unroll
            for (int rr = 0; rr < 4; ++rr) {
                int lrh  = 2 * rr + (lane >> 5);
                int node = n0 + wrow0 + 8 * h + lrh;
                float4 x = *(const float4*)(fA + lrh * DF + (lane & 31) * 4);
                if (node < N)
                    *(float4*)(outp + (size_t)node * 256 + (lane & 31) * 4) = x;
            }
            asm volatile("" ::: "memory");
        }
    }
}

// masks from post-fill base diffs: num_types = (deg_a>0) + (deg_b>0)
__global__ void __launch_bounds__(256) mask_kernel(
    const int* __restrict__ base, float* __restrict__ nt6,
    float* __restrict__ nt8, int N6, int N8)
{
    int i = blockIdx.x * blockDim.x + threadIdx.x;
    if (i < N6) {
        int g66 = i, g86 = N6 + i;
        int d66 = base[g66] - (g66 ? base[g66 - 1] : 0);
        int d86 = base[g86] - base[g86 - 1];
        nt6[i] = (float)((d66 > 0) + (d86 > 0));
    }
    if (i < N8) {
        int g68 = 2 * N6 + i, g88 = 2 * N6 + N8 + i;
        int d68 = base[g68] - base[g68 - 1];
        int d88 = base[g88] - base[g88 - 1];
        nt8[i] = (float)((d68 > 0) + (d88 > 0));
    }
}

extern "C" void kernel_launch(void* const* d_in, const int* in_sizes, int n_in,
                              void* d_out, int out_size, void* d_ws, size_t ws_size,
                              hipStream_t stream)
{
    const float* msg66 = (const float*)d_in[0];
    const float* msg68 = (const float*)d_in[1];
    const float* msg86 = (const float*)d_in[2];
    const float* msg88 = (const float*)d_in[3];
    const float* W66   = (const float*)d_in[4];
    const float* W68   = (const float*)d_in[5];
    const float* W86   = (const float*)d_in[6];
    const float* W88   = (const float*)d_in[7];
    const int*   ei66  = (const int*)d_in[8];
    const int*   ei68  = (const int*)d_in[9];
    const int*   ei86  = (const int*)d_in[10];
    const int*   ei88  = (const int*)d_in[11];

    int E66 = in_sizes[8]  / 2;
    int E68 = in_sizes[9]  / 2;
    int E86 = in_sizes[10] / 2;
    int E88 = in_sizes[11] / 2;
    int Etot = E66 + E86 + E68 + E88;

    size_t S  = (size_t)out_size / 257;       // out = 257*(N6+N8)
    int    N6 = (int)(S / 2);
    int    N8 = (int)(S - S / 2);
    int    M  = 2 * N6 + 2 * N8;

    float* out  = (float*)d_out;
    float* out6 = out;                          // (N6, 2, 128)
    float* out8 = out + (size_t)N6 * 256;       // (N8, 2, 128)
    float* nt6  = out + (size_t)(N6 + N8) * 256;
    float* nt8  = nt6 + N6;

    int* base = (int*)d_ws;                     // [M]
    int* bsum = base + M;                       // [MAXB]
    int* csr  = bsum + MAXB;                    // [Etot]

    int NB = (M + EPB - 1) / EPB;               // scan chunks (M=400K -> 391)

    hipMemsetAsync(base, 0, (size_t)M * sizeof(int), stream);

    int eg = (Etot + 255) / 256;
    if (eg > 4096) eg = 4096;
    count_kernel<<<dim3(eg), dim3(256), 0, stream>>>(
        ei66, ei86, ei68, ei88, E66, E86, E68, E88, N6, N8, base);

    scan1_kernel<<<dim3(NB), dim3(256), 0, stream>>>(base, M, bsum);
    scan2_kernel<<<dim3(1),  dim3(256), 0, stream>>>(bsum, NB);
    scan3_kernel<<<dim3(NB), dim3(256), 0, stream>>>(base, M, bsum);

    fill_kernel<<<dim3(eg), dim3(256), 0, stream>>>(
        ei66, ei86, ei68, ei88, E66, E86, E68, E88, N6, N8, base, csr);

    int t6 = (N6 + TPB - 1) / TPB, t8 = (N8 + TPB - 1) / TPB;
    AllParams P;
    P.msg[0] = msg66; P.Wm[0] = W66; P.outp[0] = out6;       P.gb[0] = 0;           P.eb[0] = 0;                P.N[0] = N6;
    P.msg[1] = msg86; P.Wm[1] = W86; P.outp[1] = out6 + 128; P.gb[1] = N6;          P.eb[1] = E66;              P.N[1] = N6;
    P.msg[2] = msg68; P.Wm[2] = W68; P.outp[2] = out8;       P.gb[2] = 2 * N6;      P.eb[2] = E66 + E86;        P.N[2] = N8;
    P.msg[3] = msg88; P.Wm[3] = W88; P.outp[3] = out8 + 128; P.gb[3] = 2 * N6 + N8; P.eb[3] = E66 + E86 + E68;  P.N[3] = N8;
    P.cum[0] = 0;
    P.cum[1] = t6;
    P.cum[2] = 2 * t6;
    P.cum[3] = 2 * t6 + t8;
    P.cum[4] = 2 * t6 + 2 * t8;

    int G = (P.cum[4] + 1) / 2;                 // 2 tiles per block
    gather_mfma_kernel<<<dim3(G), dim3(256), 0, stream>>>(base, csr, P);

    int Nmax = (N6 > N8) ? N6 : N8;
    mask_kernel<<<dim3((Nmax + 255) / 256), dim3(256), 0, stream>>>(
        base, nt6, nt8, N6, N8);
}

// Round 11
// 442.616 us; speedup vs baseline: 3.7454x; 1.0363x over previous
//
#include <hip/hip_runtime.h>

#define DF    128   // feature dim
#define EPB   1024  // elements per scan block
#define MAXB  512   // max level-2 scan width (supports M <= 524288)
#define TPB   64    // nodes per tile
#define CAP   512   // staged edge-ids per tile (mean ~256)

typedef __attribute__((ext_vector_type(8))) short short8;
typedef __attribute__((ext_vector_type(4))) float f32x4;

__device__ __forceinline__ unsigned short f2bf(float x) {
    unsigned u = __float_as_uint(x);
    u = (u + 0x7FFFu + ((u >> 16) & 1u)) >> 16;   // RNE
    return (unsigned short)u;
}
__device__ __forceinline__ unsigned pack2bf(float a, float b) {
    return (unsigned)f2bf(a) | ((unsigned)f2bf(b) << 16);
}
__device__ __forceinline__ int rfl(int x) {
    return __builtin_amdgcn_readfirstlane(x);
}

struct AllParams {
    const float* msg[4];
    const float* Wm[4];
    float*       outp[4];
    int gb[4];
    int eb[4];
    int N[4];
    int tcnt[4];   // tiles per type
    int cumB[5];   // cumulative BLOCK counts (2 tiles/block); cumB[4] = grid
};

// ===========================================================================
// CSR build: count degrees -> exclusive scan -> place edge ids (row-packed).
// csr entry = gid | (dst & 63) << 26   (tile-local row in high 6 bits)
// ===========================================================================

__global__ void __launch_bounds__(256) count_kernel(
    const int* __restrict__ ei66, const int* __restrict__ ei86,
    const int* __restrict__ ei68, const int* __restrict__ ei88,
    int E66, int E86, int E68, int E88, int N6, int N8,
    int* __restrict__ base)
{
    int Etot = E66 + E86 + E68 + E88;
    for (int gid = blockIdx.x * 256 + threadIdx.x; gid < Etot;
         gid += gridDim.x * 256) {
        int le = gid, nb, dst;
        if (le < E66)               { dst = ei66[2 * le + 1]; nb = 0; }
        else if ((le -= E66) < E86) { dst = ei86[2 * le + 1]; nb = N6; }
        else if ((le -= E86) < E68) { dst = ei68[2 * le + 1]; nb = 2 * N6; }
        else { le -= E68;             dst = ei88[2 * le + 1]; nb = 2 * N6 + N8; }
        atomicAdd(base + nb + dst, 1);
    }
}

__global__ void __launch_bounds__(256) scan1_kernel(
    int* __restrict__ data, int M, int* __restrict__ bsum)
{
    __shared__ int ts[256];
    int t = threadIdx.x;
    int i0 = blockIdx.x * EPB + t * 4;
    int v0 = 0, v1 = 0, v2 = 0, v3 = 0;
    if (i0 + 3 < M) {
        int4 q = *(const int4*)(data + i0);
        v0 = q.x; v1 = q.y; v2 = q.z; v3 = q.w;
    } else {
        if (i0     < M) v0 = data[i0];
        if (i0 + 1 < M) v1 = data[i0 + 1];
        if (i0 + 2 < M) v2 = data[i0 + 2];
    }
    int sum = v0 + v1 + v2 + v3;
    ts[t] = sum;
    __syncthreads();
    for (int off = 1; off < 256; off <<= 1) {
        int x = (t >= off) ? ts[t - off] : 0;
        __syncthreads();
        ts[t] += x;
        __syncthreads();
    }
    int excl = ts[t] - sum;
    if (t == 255) bsum[blockIdx.x] = ts[255];
    int w0 = excl, w1 = excl + v0, w2 = w1 + v1, w3 = w2 + v2;
    if (i0 + 3 < M) {
        *(int4*)(data + i0) = make_int4(w0, w1, w2, w3);
    } else {
        if (i0     < M) data[i0]     = w0;
        if (i0 + 1 < M) data[i0 + 1] = w1;
        if (i0 + 2 < M) data[i0 + 2] = w2;
    }
}

__global__ void __launch_bounds__(256) scan2_kernel(int* __restrict__ bsum, int nb)
{
    __shared__ int s[MAXB];
    int t = threadIdx.x;
    s[t]       = (t       < nb) ? bsum[t]       : 0;
    s[t + 256] = (t + 256 < nb) ? bsum[t + 256] : 0;
    __syncthreads();
    int o0 = s[t], o1 = s[t + 256];
    for (int off = 1; off < MAXB; off <<= 1) {
        int a = (t       >= off) ? s[t       - off] : 0;
        int b = (t + 256 >= off) ? s[t + 256 - off] : 0;
        __syncthreads();
        s[t] += a; s[t + 256] += b;
        __syncthreads();
    }
    if (t       < nb) bsum[t]       = s[t]       - o0;
    if (t + 256 < nb) bsum[t + 256] = s[t + 256] - o1;
}

__global__ void __launch_bounds__(256) scan3_kernel(
    int* __restrict__ data, int M, const int* __restrict__ bsum)
{
    int add = bsum[blockIdx.x];
    if (add == 0) return;
    int i0 = blockIdx.x * EPB + threadIdx.x * 4;
    if (i0 + 3 < M) {
        int4 q = *(const int4*)(data + i0);
        q.x += add; q.y += add; q.z += add; q.w += add;
        *(int4*)(data + i0) = q;
    } else {
        if (i0     < M) data[i0]     += add;
        if (i0 + 1 < M) data[i0 + 1] += add;
        if (i0 + 2 < M) data[i0 + 2] += add;
    }
}

__global__ void __launch_bounds__(256) fill_kernel(
    const int* __restrict__ ei66, const int* __restrict__ ei86,
    const int* __restrict__ ei68, const int* __restrict__ ei88,
    int E66, int E86, int E68, int E88, int N6, int N8,
    int* __restrict__ base, int* __restrict__ csr)
{
    int Etot = E66 + E86 + E68 + E88;
    for (int gid = blockIdx.x * 256 + threadIdx.x; gid < Etot;
         gid += gridDim.x * 256) {
        int le = gid, nb, dst;
        if (le < E66)               { dst = ei66[2 * le + 1]; nb = 0; }
        else if ((le -= E66) < E86) { dst = ei86[2 * le + 1]; nb = N6; }
        else if ((le -= E86) < E68) { dst = ei68[2 * le + 1]; nb = 2 * N6; }
        else { le -= E68;             dst = ei88[2 * le + 1]; nb = 2 * N6 + N8; }
        int pos = atomicAdd(base + nb + dst, 1);
        csr[pos] = (int)((unsigned)gid | (((unsigned)(dst & 63)) << 26));
    }
}

// ===========================================================================
// Fused kernel: 512 threads = 8 waves = 2 CONCURRENT 64-node tiles per block
// (waves 0-3 -> tile 2b, waves 4-7 -> tile 2b+1), one shared Wt stage.
// Per-type block partition (cumB) keeps each block single-type.
// LDS ~70 KB -> 2 blocks/CU = 16 waves/CU (vs 12 before).
// Per wave (16 rows): flat slot walk, 4-buffer rotation (3 msg batches in
// flight), packed-row boundaries, swizzled bf16 flush -> MFMA -> mean ->
// coalesced float4 store via LDS transpose.
// Swizzle: element k of row m at short idx m*128 + (((k>>3)^(m&7))<<3)+(k&7)
// ===========================================================================
__global__ void __launch_bounds__(512, 4) gather_mfma_kernel(
    const int* __restrict__ base, const int* __restrict__ csr, AllParams P)
{
    __shared__ alignas(16) short Wt[DF * DF];        // 32 KB, swizzled W^T
    __shared__ alignas(16) short At[8][16 * DF];     // 32 KB, per-wave A-tiles
    __shared__ int eids[2][CAP];                     //  4 KB
    __shared__ int ends_s[2][TPB + 1];

    const int t    = threadIdx.x;
    const int lane = t & 63;
    const int w    = t >> 6;        // 0..7
    const int hf   = w >> 2;        // tile half 0/1
    const int wl   = w & 3;         // wave within half
    const int tl   = t & 255;       // thread within half
    const int l15  = lane & 15;
    const int lg   = lane >> 4;
    short* Atw = At[w];

    const int bb = blockIdx.x;
    const int ty = (bb >= P.cumB[2]) ? ((bb >= P.cumB[3]) ? 3 : 2)
                                     : ((bb >= P.cumB[1]) ? 1 : 0);
    const float* msg = P.msg[ty];
    const int gbase = P.gb[ty], ebase = P.eb[ty], N = P.N[ty];
    const int tile  = (bb - P.cumB[ty]) * 2 + hf;
    const bool act  = (tile < P.tcnt[ty]);
    const int n0    = tile * TPB;

    // ---- stage swizzled bf16 W^T (all 8 waves) ----
    {
        const float* Wm = P.Wm[ty];
        for (int idx = t; idx < 2048; idx += 512) {
            int k0 = (idx >> 5) << 1;        // even k
            int ng = (idx & 31) << 2;        // n group base
            float4 wa = *(const float4*)(Wm + (size_t)k0 * DF + ng);
            float4 wb = *(const float4*)(Wm + (size_t)(k0 + 1) * DF + ng);
            float wav[4] = {wa.x, wa.y, wa.z, wa.w};
            float wbv[4] = {wb.x, wb.y, wb.z, wb.w};
            int cb = k0 >> 3, kl = k0 & 7;
            #pragma unroll
            for (int j = 0; j < 4; ++j) {
                int n = ng + j;
                int chunk = cb ^ (n & 7);
                *(unsigned*)(Wt + n * DF + chunk * 8 + kl) =
                    pack2bf(wav[j], wbv[j]);
            }
        }
    }

    // ---- stage cumulative ends + edge ids for this half's tile ----
    if (tl <= TPB) {
        int v = 0;
        if (act) {
            int nn = n0 + tl - 1;
            if (nn >= N) nn = N - 1;
            int gi = gbase + nn;
            v = (gi >= 0) ? base[gi] : 0;
        }
        ends_s[hf][tl] = v;
    }
    if (act) {
        int gi0   = gbase + n0 - 1;
        int myts0 = (gi0 >= 0) ? base[gi0] : 0;
        int nn = n0 + TPB - 1; if (nn >= N) nn = N - 1;
        int myts1 = base[gbase + nn];
        int tot_all = myts1 - myts0;
        for (int i = tl; i < tot_all && i < CAP; i += 256)
            eids[hf][i] = csr[myts0 + i];
    }
    __syncthreads();

    const int ts0   = ends_s[hf][0];
    const int wrow0 = wl * 16;
    const int s0    = ends_s[hf][wrow0];
    const int s1    = ends_s[hf][wrow0 + 16];
    const int lbase = s0 - ts0;
    const int tot   = s1 - s0;
    int   cur = wrow0;
    float ax = 0.f, ay = 0.f;

#define LDE(eX, sb) { _Pragma("unroll")                                       \
    for (int j = 0; j < 8; ++j) {                                             \
        int ls = (sb) + j; ls = (ls < tot) ? ls : (tot - 1);                  \
        int gs = lbase + ls;                                                  \
        eX[j] = (gs < CAP) ? eids[hf][gs] : csr[ts0 + gs]; } }

#define LDM(vX, eX) { _Pragma("unroll")                                       \
    for (int j = 0; j < 8; ++j) {                                             \
        int idx = (int)(((unsigned)eX[j]) & 0x03FFFFFFu) - ebase;             \
        vX[j] = *(const float2*)(msg + (size_t)idx * DF + 2 * lane); } }

#define FLUSHR() {                                                            \
    int lr_ = cur & 15;                                                       \
    *(unsigned*)(Atw + lr_ * DF + ((((lane >> 2) ^ (lr_ & 7))) << 3)          \
                 + ((lane & 3) << 1)) = pack2bf(ax, ay);                      \
    ax = 0.f; ay = 0.f; ++cur; }

#define CONSB(vX, eX, sb) { _Pragma("unroll")                                 \
    for (int j = 0; j < 8; ++j) {                                             \
        if ((sb) + j < tot) {                                                 \
            int rl = wrow0 + (int)((((unsigned)rfl(eX[j])) >> 26) & 15u);     \
            while (cur < rl) FLUSHR();                                        \
            ax += vX[j].x; ay += vX[j].y; } } }

    if (tot > 0) {
        int eA[8], eB[8], eC[8], eD[8];
        float2 vA[8], vB[8], vC[8], vD[8];
        const int nb = (tot + 7) >> 3;

        LDE(eA, 0); LDE(eB, 8); LDE(eC, 16);
        LDM(vA, eA); LDM(vB, eB); LDM(vC, eC);
        int ib = 0;
        while (true) {
            LDE(eD, ib * 8 + 24); LDM(vD, eD); CONSB(vA, eA, ib * 8);
            if (++ib >= nb) break;
            LDE(eA, ib * 8 + 24); LDM(vA, eA); CONSB(vB, eB, ib * 8);
            if (++ib >= nb) break;
            LDE(eB, ib * 8 + 24); LDM(vB, eB); CONSB(vC, eC, ib * 8);
            if (++ib >= nb) break;
            LDE(eC, ib * 8 + 24); LDM(vC, eC); CONSB(vD, eD, ib * 8);
            if (++ib >= nb) break;
        }
    }
    while (cur < wrow0 + 16) FLUSHR();
#undef LDE
#undef LDM
#undef FLUSHR
#undef CONSB

    // ---------------- MFMA: wave's 16 rows x 128 cols ------------------
    // A(m,k): m=lane&15, k=32*kk+8*lg+j ; B(k,n): n=lane&15, same k.
    // D: col=lane&15, row=lg*4+reg.
    f32x4 acc[8];
    #pragma unroll
    for (int j = 0; j < 8; ++j) acc[j] = (f32x4){0.f, 0.f, 0.f, 0.f};

    #pragma unroll
    for (int kk = 0; kk < 4; ++kk) {
        int c = kk * 4 + lg;
        short8 av = *(const short8*)(Atw + l15 * DF + ((c ^ (l15 & 7)) << 3));
        #pragma unroll
        for (int j = 0; j < 8; ++j) {
            int n = j * 16 + l15;
            short8 bv = *(const short8*)(Wt + n * DF + ((c ^ (n & 7)) << 3));
            acc[j] = __builtin_amdgcn_mfma_f32_16x16x32_bf16(
                av, bv, acc[j], 0, 0, 0);
        }
    }

    // mean on f32 accumulators ((sum@W)/deg == (sum/deg)@W)
    #pragma unroll
    for (int q = 0; q < 4; ++q) {
        int lrow = wrow0 + lg * 4 + q;
        int dg = ends_s[hf][lrow + 1] - ends_s[hf][lrow];
        float inv = (dg > 0) ? (1.0f / (float)dg) : 0.0f;
        #pragma unroll
        for (int j = 0; j < 8; ++j) acc[j][q] *= inv;
    }

    // ------------- store: LDS transpose -> coalesced float4 -----------
    float* fA = (float*)Atw;           // wave-private scratch (4096B)
    float* outp = P.outp[ty];
    #pragma unroll
    for (int h = 0; h < 2; ++h) {
        if ((lg >> 1) == h) {
            int lr = (lg & 1) << 2;
            #pragma unroll
            for (int q = 0; q < 4; ++q)
                #pragma unroll
                for (int j = 0; j < 8; ++j)
                    fA[(lr + q) * DF + j * 16 + l15] = acc[j][q];
        }
        asm volatile("" ::: "memory");
        #pragma unroll
        for (int rr = 0; rr < 4; ++rr) {
            int lrh  = 2 * rr + (lane >> 5);
            int node = n0 + wrow0 + 8 * h + lrh;
            float4 x = *(const float4*)(fA + lrh * DF + (lane & 31) * 4);
            if (act && node < N)
                *(float4*)(outp + (size_t)node * 256 + (lane & 31) * 4) = x;
        }
        asm volatile("" ::: "memory");
    }
}

// masks from post-fill base diffs: num_types = (deg_a>0) + (deg_b>0)
__global__ void __launch_bounds__(256) mask_kernel(
    const int* __restrict__ base, float* __restrict__ nt6,
    float* __restrict__ nt8, int N6, int N8)
{
    int i = blockIdx.x * blockDim.x + threadIdx.x;
    if (i < N6) {
        int g66 = i, g86 = N6 + i;
        int d66 = base[g66] - (g66 ? base[g66 - 1] : 0);
        int d86 = base[g86] - base[g86 - 1];
        nt6[i] = (float)((d66 > 0) + (d86 > 0));
    }
    if (i < N8) {
        int g68 = 2 * N6 + i, g88 = 2 * N6 + N8 + i;
        int d68 = base[g68] - base[g68 - 1];
        int d88 = base[g88] - base[g88 - 1];
        nt8[i] = (float)((d68 > 0) + (d88 > 0));
    }
}

extern "C" void kernel_launch(void* const* d_in, const int* in_sizes, int n_in,
                              void* d_out, int out_size, void* d_ws, size_t ws_size,
                              hipStream_t stream)
{
    const float* msg66 = (const float*)d_in[0];
    const float* msg68 = (const float*)d_in[1];
    const float* msg86 = (const float*)d_in[2];
    const float* msg88 = (const float*)d_in[3];
    const float* W66   = (const float*)d_in[4];
    const float* W68   = (const float*)d_in[5];
    const float* W86   = (const float*)d_in[6];
    const float* W88   = (const float*)d_in[7];
    const int*   ei66  = (const int*)d_in[8];
    const int*   ei68  = (const int*)d_in[9];
    const int*   ei86  = (const int*)d_in[10];
    const int*   ei88  = (const int*)d_in[11];

    int E66 = in_sizes[8]  / 2;
    int E68 = in_sizes[9]  / 2;
    int E86 = in_sizes[10] / 2;
    int E88 = in_sizes[11] / 2;
    int Etot = E66 + E86 + E68 + E88;

    size_t S  = (size_t)out_size / 257;       // out = 257*(N6+N8)
    int    N6 = (int)(S / 2);
    int    N8 = (int)(S - S / 2);
    int    M  = 2 * N6 + 2 * N8;

    float* out  = (float*)d_out;
    float* out6 = out;                          // (N6, 2, 128)
    float* out8 = out + (size_t)N6 * 256;       // (N8, 2, 128)
    float* nt6  = out + (size_t)(N6 + N8) * 256;
    float* nt8  = nt6 + N6;

    int* base = (int*)d_ws;                     // [M]
    int* bsum = base + M;                       // [MAXB]
    int* csr  = bsum + MAXB;                    // [Etot]

    int NB = (M + EPB - 1) / EPB;               // scan chunks (M=400K -> 391)

    hipMemsetAsync(base, 0, (size_t)M * sizeof(int), stream);

    int eg = (Etot + 255) / 256;
    if (eg > 4096) eg = 4096;
    count_kernel<<<dim3(eg), dim3(256), 0, stream>>>(
        ei66, ei86, ei68, ei88, E66, E86, E68, E88, N6, N8, base);

    scan1_kernel<<<dim3(NB), dim3(256), 0, stream>>>(base, M, bsum);
    scan2_kernel<<<dim3(1),  dim3(256), 0, stream>>>(bsum, NB);
    scan3_kernel<<<dim3(NB), dim3(256), 0, stream>>>(base, M, bsum);

    fill_kernel<<<dim3(eg), dim3(256), 0, stream>>>(
        ei66, ei86, ei68, ei88, E66, E86, E68, E88, N6, N8, base, csr);

    int t6 = (N6 + TPB - 1) / TPB, t8 = (N8 + TPB - 1) / TPB;
    int b6 = (t6 + 1) / 2,        b8 = (t8 + 1) / 2;
    AllParams P;
    P.msg[0] = msg66; P.Wm[0] = W66; P.outp[0] = out6;       P.gb[0] = 0;           P.eb[0] = 0;                P.N[0] = N6; P.tcnt[0] = t6;
    P.msg[1] = msg86; P.Wm[1] = W86; P.outp[1] = out6 + 128; P.gb[1] = N6;          P.eb[1] = E66;              P.N[1] = N6; P.tcnt[1] = t6;
    P.msg[2] = msg68; P.Wm[2] = W68; P.outp[2] = out8;       P.gb[2] = 2 * N6;      P.eb[2] = E66 + E86;        P.N[2] = N8; P.tcnt[2] = t8;
    P.msg[3] = msg88; P.Wm[3] = W88; P.outp[3] = out8 + 128; P.gb[3] = 2 * N6 + N8; P.eb[3] = E66 + E86 + E68;  P.N[3] = N8; P.tcnt[3] = t8;
    P.cumB[0] = 0;
    P.cumB[1] = b6;
    P.cumB[2] = 2 * b6;
    P.cumB[3] = 2 * b6 + b8;
    P.cumB[4] = 2 * b6 + 2 * b8;

    gather_mfma_kernel<<<dim3(P.cumB[4]), dim3(512), 0, stream>>>(base, csr, P);

    int Nmax = (N6 > N8) ? N6 : N8;
    mask_kernel<<<dim3((Nmax + 255) / 256), dim3(256), 0, stream>>>(
        base, nt6, nt8, N6, N8);
}

// Round 13
// 432.178 us; speedup vs baseline: 3.8359x; 1.0242x over previous
//
#include <hip/hip_runtime.h>

#define DF    128   // feature dim
#define EPB   1024  // elements per scan block
#define MAXB  512   // max level-2 scan width (supports M <= 524288)
#define TPB   64    // nodes per tile
#define CAP   640   // staged edge-ids per tile (mean ~256)

typedef __attribute__((ext_vector_type(8))) short short8;
typedef __attribute__((ext_vector_type(4))) float f32x4;

__device__ __forceinline__ unsigned short f2bf(float x) {
    unsigned u = __float_as_uint(x);
    u = (u + 0x7FFFu + ((u >> 16) & 1u)) >> 16;   // RNE
    return (unsigned short)u;
}
__device__ __forceinline__ unsigned pack2bf(float a, float b) {
    return (unsigned)f2bf(a) | ((unsigned)f2bf(b) << 16);
}
__device__ __forceinline__ int rfl(int x) {
    return __builtin_amdgcn_readfirstlane(x);
}

struct AllParams {
    const float* msg[4];
    const float* Wm[4];
    float*       outp[4];
    int gb[4];
    int eb[4];
    int N[4];
    int tcnt[4];   // tiles per type
    int cumB[5];   // cumulative BLOCK counts (2 tiles/block); cumB[4] = grid
};

// ===========================================================================
// CSR build: count degrees -> 3-kernel scan (proven) -> place edge ids.
// csr entry = gid | (dst & 63) << 26   (tile-local row in high 6 bits)
// ===========================================================================

__global__ void __launch_bounds__(256) count_kernel(
    const int* __restrict__ ei66, const int* __restrict__ ei86,
    const int* __restrict__ ei68, const int* __restrict__ ei88,
    int E66, int E86, int E68, int E88, int N6, int N8,
    int* __restrict__ base)
{
    int Etot = E66 + E86 + E68 + E88;
    for (int gid = blockIdx.x * 256 + threadIdx.x; gid < Etot;
         gid += gridDim.x * 256) {
        int le = gid, nb, dst;
        if (le < E66)               { dst = ei66[2 * le + 1]; nb = 0; }
        else if ((le -= E66) < E86) { dst = ei86[2 * le + 1]; nb = N6; }
        else if ((le -= E86) < E68) { dst = ei68[2 * le + 1]; nb = 2 * N6; }
        else { le -= E68;             dst = ei88[2 * le + 1]; nb = 2 * N6 + N8; }
        atomicAdd(base + nb + dst, 1);
    }
}

__global__ void __launch_bounds__(256) scan1_kernel(
    int* __restrict__ data, int M, int* __restrict__ bsum)
{
    __shared__ int ts[256];
    int t = threadIdx.x;
    int i0 = blockIdx.x * EPB + t * 4;
    int v0 = 0, v1 = 0, v2 = 0, v3 = 0;
    if (i0 + 3 < M) {
        int4 q = *(const int4*)(data + i0);
        v0 = q.x; v1 = q.y; v2 = q.z; v3 = q.w;
    } else {
        if (i0     < M) v0 = data[i0];
        if (i0 + 1 < M) v1 = data[i0 + 1];
        if (i0 + 2 < M) v2 = data[i0 + 2];
    }
    int sum = v0 + v1 + v2 + v3;
    ts[t] = sum;
    __syncthreads();
    for (int off = 1; off < 256; off <<= 1) {
        int x = (t >= off) ? ts[t - off] : 0;
        __syncthreads();
        ts[t] += x;
        __syncthreads();
    }
    int excl = ts[t] - sum;
    if (t == 255) bsum[blockIdx.x] = ts[255];
    int w0 = excl, w1 = excl + v0, w2 = w1 + v1, w3 = w2 + v2;
    if (i0 + 3 < M) {
        *(int4*)(data + i0) = make_int4(w0, w1, w2, w3);
    } else {
        if (i0     < M) data[i0]     = w0;
        if (i0 + 1 < M) data[i0 + 1] = w1;
        if (i0 + 2 < M) data[i0 + 2] = w2;
    }
}

__global__ void __launch_bounds__(256) scan2_kernel(int* __restrict__ bsum, int nb)
{
    __shared__ int s[MAXB];
    int t = threadIdx.x;
    s[t]       = (t       < nb) ? bsum[t]       : 0;
    s[t + 256] = (t + 256 < nb) ? bsum[t + 256] : 0;
    __syncthreads();
    int o0 = s[t], o1 = s[t + 256];
    for (int off = 1; off < MAXB; off <<= 1) {
        int a = (t       >= off) ? s[t       - off] : 0;
        int b = (t + 256 >= off) ? s[t + 256 - off] : 0;
        __syncthreads();
        s[t] += a; s[t + 256] += b;
        __syncthreads();
    }
    if (t       < nb) bsum[t]       = s[t]       - o0;
    if (t + 256 < nb) bsum[t + 256] = s[t + 256] - o1;
}

__global__ void __launch_bounds__(256) scan3_kernel(
    int* __restrict__ data, int M, const int* __restrict__ bsum)
{
    int add = bsum[blockIdx.x];
    if (add == 0) return;
    int i0 = blockIdx.x * EPB + threadIdx.x * 4;
    if (i0 + 3 < M) {
        int4 q = *(const int4*)(data + i0);
        q.x += add; q.y += add; q.z += add; q.w += add;
        *(int4*)(data + i0) = q;
    } else {
        if (i0     < M) data[i0]     += add;
        if (i0 + 1 < M) data[i0 + 1] += add;
        if (i0 + 2 < M) data[i0 + 2] += add;
    }
}

__global__ void __launch_bounds__(256) fill_kernel(
    const int* __restrict__ ei66, const int* __restrict__ ei86,
    const int* __restrict__ ei68, const int* __restrict__ ei88,
    int E66, int E86, int E68, int E88, int N6, int N8,
    int* __restrict__ base, int* __restrict__ csr)
{
    int Etot = E66 + E86 + E68 + E88;
    for (int gid = blockIdx.x * 256 + threadIdx.x; gid < Etot;
         gid += gridDim.x * 256) {
        int le = gid, nb, dst;
        if (le < E66)               { dst = ei66[2 * le + 1]; nb = 0; }
        else if ((le -= E66) < E86) { dst = ei86[2 * le + 1]; nb = N6; }
        else if ((le -= E86) < E68) { dst = ei68[2 * le + 1]; nb = 2 * N6; }
        else { le -= E68;             dst = ei88[2 * le + 1]; nb = 2 * N6 + N8; }
        int pos = atomicAdd(base + nb + dst, 1);
        csr[pos] = (int)((unsigned)gid | (((unsigned)(dst & 63)) << 26));
    }
}

// ===========================================================================
// Fused gather+MFMA: 512 threads = 2 concurrent 64-node tiles per block.
// Per wave (16 rows): flat slot walk, depth-4 msg pipeline (5 v-buffers,
// ids from LDS so each consume drains only its own batch), per-batch row
// bits packed into one scalar word at load time (consume = SALU bookkeeping),
// swizzled bf16 flush -> MFMA -> mean -> coalesced float4 store.
// Swizzle: element k of row m at short idx m*128 + (((k>>3)^(m&7))<<3)+(k&7)
// ===========================================================================
__global__ void __launch_bounds__(512, 4) gather_mfma_kernel(
    const int* __restrict__ base, const int* __restrict__ csr, AllParams P)
{
    __shared__ alignas(16) short Wt[DF * DF];        // 32 KB, swizzled W^T
    __shared__ alignas(16) short At[8][16 * DF];     // 32 KB, per-wave A-tiles
    __shared__ int eids[2][CAP];                     //  5 KB
    __shared__ int ends_s[2][TPB + 1];

    const int t    = threadIdx.x;
    const int lane = t & 63;
    const int w    = t >> 6;        // 0..7
    const int hf   = w >> 2;        // tile half 0/1
    const int wl   = w & 3;         // wave within half
    const int tl   = t & 255;       // thread within half
    const int l15  = lane & 15;
    const int lg   = lane >> 4;
    short* Atw = At[w];

    const int bb = blockIdx.x;
    const int ty = (bb >= P.cumB[2]) ? ((bb >= P.cumB[3]) ? 3 : 2)
                                     : ((bb >= P.cumB[1]) ? 1 : 0);
    const float* msg = P.msg[ty];
    const int gbase = P.gb[ty], ebase = P.eb[ty], N = P.N[ty];
    const int tile  = (bb - P.cumB[ty]) * 2 + hf;
    const bool act  = (tile < P.tcnt[ty]);
    const int n0    = tile * TPB;

    // ---- stage swizzled bf16 W^T (all 8 waves) ----
    {
        const float* Wm = P.Wm[ty];
        for (int idx = t; idx < 2048; idx += 512) {
            int k0 = (idx >> 5) << 1;        // even k
            int ng = (idx & 31) << 2;        // n group base
            float4 wa = *(const float4*)(Wm + (size_t)k0 * DF + ng);
            float4 wb = *(const float4*)(Wm + (size_t)(k0 + 1) * DF + ng);
            float wav[4] = {wa.x, wa.y, wa.z, wa.w};
            float wbv[4] = {wb.x, wb.y, wb.z, wb.w};
            int cb = k0 >> 3, kl = k0 & 7;
            #pragma unroll
            for (int j = 0; j < 4; ++j) {
                int n = ng + j;
                int chunk = cb ^ (n & 7);
                *(unsigned*)(Wt + n * DF + chunk * 8 + kl) =
                    pack2bf(wav[j], wbv[j]);
            }
        }
    }

    // ---- stage cumulative ends + edge ids for this half's tile ----
    if (tl <= TPB) {
        int v = 0;
        if (act) {
            int nn = n0 + tl - 1;
            if (nn >= N) nn = N - 1;
            int gi = gbase + nn;
            v = (gi >= 0) ? base[gi] : 0;
        }
        ends_s[hf][tl] = v;
    }
    if (act) {
        int gi0   = gbase + n0 - 1;
        int myts0 = (gi0 >= 0) ? base[gi0] : 0;
        int nn = n0 + TPB - 1; if (nn >= N) nn = N - 1;
        int myts1 = base[gbase + nn];
        int tot_all = myts1 - myts0;
        for (int i = tl; i < tot_all && i < CAP; i += 256)
            eids[hf][i] = csr[myts0 + i];
    }
    __syncthreads();

    const int ts0   = ends_s[hf][0];
    const int wrow0 = wl * 16;
    const int s0    = ends_s[hf][wrow0];
    const int s1    = ends_s[hf][wrow0 + 16];
    const int lbase = s0 - ts0;
    const int tot   = s1 - s0;
    int   cur = wrow0;
    float ax = 0.f, ay = 0.f;

#define LDE_F(eX, sb) { _Pragma("unroll")                                     \
    for (int j = 0; j < 8; ++j) {                                             \
        int ls = (sb) + j; ls = (ls < tot) ? ls : (tot - 1);                  \
        eX[j] = eids[hf][lbase + ls]; } }

#define LDE_S(eX, sb) { _Pragma("unroll")                                     \
    for (int j = 0; j < 8; ++j) {                                             \
        int ls = (sb) + j; ls = (ls < tot) ? ls : (tot - 1);                  \
        int gs = lbase + ls;                                                  \
        eX[j] = (gs < CAP) ? eids[hf][gs] : csr[ts0 + gs]; } }

    // load msg batch; extract per-batch packed row word (scalar, 4b/slot)
#define LDMR(vX, rwX, eT) {                                                   \
    rwX = 0;                                                                  \
    _Pragma("unroll")                                                         \
    for (int j = 0; j < 8; ++j) {                                             \
        unsigned ee = (unsigned)rfl(eT[j]);                                   \
        rwX |= (int)((((ee >> 26) & 63u) - (unsigned)wrow0) & 15u) << (4*j);  \
        int idx = (int)(ee & 0x03FFFFFFu) - ebase;                            \
        vX[j] = *(const float2*)(msg + (size_t)idx * DF + 2 * lane); } }

#define FLUSHR() {                                                            \
    int lr_ = cur & 15;                                                       \
    *(unsigned*)(Atw + lr_ * DF + ((((lane >> 2) ^ (lr_ & 7))) << 3)          \
                 + ((lane & 3) << 1)) = pack2bf(ax, ay);                      \
    ax = 0.f; ay = 0.f; ++cur; }

#define CONSB(vX, rwX, sb) { _Pragma("unroll")                                \
    for (int j = 0; j < 8; ++j) {                                             \
        if ((sb) + j < tot) {                                                 \
            int rl = wrow0 + ((rwX >> (4*j)) & 15);                           \
            while (cur < rl) FLUSHR();                                        \
            ax += vX[j].x; ay += vX[j].y; } } }

#define WALK(LDEX) {                                                          \
    int eT[8]; int rw0, rw1, rw2, rw3, rw4;                                   \
    float2 v0[8], v1[8], v2[8], v3[8], v4[8];                                 \
    LDEX(eT, 0);  LDMR(v0, rw0, eT);                                          \
    LDEX(eT, 8);  LDMR(v1, rw1, eT);                                          \
    LDEX(eT, 16); LDMR(v2, rw2, eT);                                          \
    LDEX(eT, 24); LDMR(v3, rw3, eT);                                          \
    const int nb = (tot + 7) >> 3;                                            \
    int ib = 0;                                                               \
    while (true) {                                                            \
        LDEX(eT, ib*8+32); LDMR(v4, rw4, eT); CONSB(v0, rw0, ib*8);           \
        if (++ib >= nb) break;                                                \
        LDEX(eT, ib*8+32); LDMR(v0, rw0, eT); CONSB(v1, rw1, ib*8);           \
        if (++ib >= nb) break;                                                \
        LDEX(eT, ib*8+32); LDMR(v1, rw1, eT); CONSB(v2, rw2, ib*8);           \
        if (++ib >= nb) break;                                                \
        LDEX(eT, ib*8+32); LDMR(v2, rw2, eT); CONSB(v3, rw3, ib*8);           \
        if (++ib >= nb) break;                                                \
        LDEX(eT, ib*8+32); LDMR(v3, rw3, eT); CONSB(v4, rw4, ib*8);           \
        if (++ib >= nb) break;                                                \
    } }

    if (tot > 0) {
        if (lbase + tot <= CAP) { WALK(LDE_F) }   // ids fully in LDS (typical)
        else                    { WALK(LDE_S) }   // rare spill fallback
    }
    while (cur < wrow0 + 16) FLUSHR();
#undef LDE_F
#undef LDE_S
#undef LDMR
#undef FLUSHR
#undef CONSB
#undef WALK

    // ---------------- MFMA: wave's 16 rows x 128 cols ------------------
    // A(m,k): m=lane&15, k=32*kk+8*lg+j ; B(k,n): n=lane&15, same k.
    // D: col=lane&15, row=lg*4+reg.
    f32x4 acc[8];
    #pragma unroll
    for (int j = 0; j < 8; ++j) acc[j] = (f32x4){0.f, 0.f, 0.f, 0.f};

    #pragma unroll
    for (int kk = 0; kk < 4; ++kk) {
        int c = kk * 4 + lg;
        short8 av = *(const short8*)(Atw + l15 * DF + ((c ^ (l15 & 7)) << 3));
        #pragma unroll
        for (int j = 0; j < 8; ++j) {
            int n = j * 16 + l15;
            short8 bv = *(const short8*)(Wt + n * DF + ((c ^ (n & 7)) << 3));
            acc[j] = __builtin_amdgcn_mfma_f32_16x16x32_bf16(
                av, bv, acc[j], 0, 0, 0);
        }
    }

    // mean on f32 accumulators ((sum@W)/deg == (sum/deg)@W)
    #pragma unroll
    for (int q = 0; q < 4; ++q) {
        int lrow = wrow0 + lg * 4 + q;
        int dg = ends_s[hf][lrow + 1] - ends_s[hf][lrow];
        float inv = (dg > 0) ? (1.0f / (float)dg) : 0.0f;
        #pragma unroll
        for (int j = 0; j < 8; ++j) acc[j][q] *= inv;
    }

    // ------------- store: LDS transpose -> coalesced float4 -----------
    float* fA = (float*)Atw;           // wave-private scratch (4096B)
    float* outp = P.outp[ty];
    #pragma unroll
    for (int h = 0; h < 2; ++h) {
        if ((lg >> 1) == h) {
            int lr = (lg & 1) << 2;
            #pragma unroll
            for (int q = 0; q < 4; ++q)
                #pragma unroll
                for (int j = 0; j < 8; ++j)
                    fA[(lr + q) * DF + j * 16 + l15] = acc[j][q];
        }
        asm volatile("" ::: "memory");
        #pragma unroll
        for (int rr = 0; rr < 4; ++rr) {
            int lrh  = 2 * rr + (lane >> 5);
            int node = n0 + wrow0 + 8 * h + lrh;
            float4 x = *(const float4*)(fA + lrh * DF + (lane & 31) * 4);
            if (act && node < N)
                *(float4*)(outp + (size_t)node * 256 + (lane & 31) * 4) = x;
        }
        asm volatile("" ::: "memory");
    }
}

// masks from post-fill base diffs: num_types = (deg_a>0) + (deg_b>0)
__global__ void __launch_bounds__(256) mask_kernel(
    const int* __restrict__ base, float* __restrict__ nt6,
    float* __restrict__ nt8, int N6, int N8)
{
    int i = blockIdx.x * blockDim.x + threadIdx.x;
    if (i < N6) {
        int g66 = i, g86 = N6 + i;
        int d66 = base[g66] - (g66 ? base[g66 - 1] : 0);
        int d86 = base[g86] - base[g86 - 1];
        nt6[i] = (float)((d66 > 0) + (d86 > 0));
    }
    if (i < N8) {
        int g68 = 2 * N6 + i, g88 = 2 * N6 + N8 + i;
        int d68 = base[g68] - base[g68 - 1];
        int d88 = base[g88] - base[g88 - 1];
        nt8[i] = (float)((d68 > 0) + (d88 > 0));
    }
}

extern "C" void kernel_launch(void* const* d_in, const int* in_sizes, int n_in,
                              void* d_out, int out_size, void* d_ws, size_t ws_size,
                              hipStream_t stream)
{
    const float* msg66 = (const float*)d_in[0];
    const float* msg68 = (const float*)d_in[1];
    const float* msg86 = (const float*)d_in[2];
    const float* msg88 = (const float*)d_in[3];
    const float* W66   = (const float*)d_in[4];
    const float* W68   = (const float*)d_in[5];
    const float* W86   = (const float*)d_in[6];
    const float* W88   = (const float*)d_in[7];
    const int*   ei66  = (const int*)d_in[8];
    const int*   ei68  = (const int*)d_in[9];
    const int*   ei86  = (const int*)d_in[10];
    const int*   ei88  = (const int*)d_in[11];

    int E66 = in_sizes[8]  / 2;
    int E68 = in_sizes[9]  / 2;
    int E86 = in_sizes[10] / 2;
    int E88 = in_sizes[11] / 2;
    int Etot = E66 + E86 + E68 + E88;

    size_t S  = (size_t)out_size / 257;       // out = 257*(N6+N8)
    int    N6 = (int)(S / 2);
    int    N8 = (int)(S - S / 2);
    int    M  = 2 * N6 + 2 * N8;

    float* out  = (float*)d_out;
    float* out6 = out;                          // (N6, 2, 128)
    float* out8 = out + (size_t)N6 * 256;       // (N8, 2, 128)
    float* nt6  = out + (size_t)(N6 + N8) * 256;
    float* nt8  = nt6 + N6;

    int* base = (int*)d_ws;                     // [M]
    int* bsum = base + M;                       // [MAXB]
    int* csr  = bsum + MAXB;                    // [Etot]

    int NB = (M + EPB - 1) / EPB;               // scan chunks (M=400K -> 391)

    hipMemsetAsync(base, 0, (size_t)M * sizeof(int), stream);

    int eg = (Etot + 255) / 256;
    if (eg > 4096) eg = 4096;
    count_kernel<<<dim3(eg), dim3(256), 0, stream>>>(
        ei66, ei86, ei68, ei88, E66, E86, E68, E88, N6, N8, base);

    scan1_kernel<<<dim3(NB), dim3(256), 0, stream>>>(base, M, bsum);
    scan2_kernel<<<dim3(1),  dim3(256), 0, stream>>>(bsum, NB);
    scan3_kernel<<<dim3(NB), dim3(256), 0, stream>>>(base, M, bsum);

    fill_kernel<<<dim3(eg), dim3(256), 0, stream>>>(
        ei66, ei86, ei68, ei88, E66, E86, E68, E88, N6, N8, base, csr);

    int t6 = (N6 + TPB - 1) / TPB, t8 = (N8 + TPB - 1) / TPB;
    int b6 = (t6 + 1) / 2,        b8 = (t8 + 1) / 2;
    AllParams P;
    P.msg[0] = msg66; P.Wm[0] = W66; P.outp[0] = out6;       P.gb[0] = 0;           P.eb[0] = 0;                P.N[0] = N6; P.tcnt[0] = t6;
    P.msg[1] = msg86; P.Wm[1] = W86; P.outp[1] = out6 + 128; P.gb[1] = N6;          P.eb[1] = E66;              P.N[1] = N6; P.tcnt[1] = t6;
    P.msg[2] = msg68; P.Wm[2] = W68; P.outp[2] = out8;       P.gb[2] = 2 * N6;      P.eb[2] = E66 + E86;        P.N[2] = N8; P.tcnt[2] = t8;
    P.msg[3] = msg88; P.Wm[3] = W88; P.outp[3] = out8 + 128; P.gb[3] = 2 * N6 + N8; P.eb[3] = E66 + E86 + E68;  P.N[3] = N8; P.tcnt[3] = t8;
    P.cumB[0] = 0;
    P.cumB[1] = b6;
    P.cumB[2] = 2 * b6;
    P.cumB[3] = 2 * b6 + b8;
    P.cumB[4] = 2 * b6 + 2 * b8;

    gather_mfma_kernel<<<dim3(P.cumB[4]), dim3(512), 0, stream>>>(base, csr, P);

    int Nmax = (N6 > N8) ? N6 : N8;
    mask_kernel<<<dim3((Nmax + 255) / 256), dim3(256), 0, stream>>>(
        base, nt6, nt8, N6, N8);
}